// Round 1
// 705.380 us; speedup vs baseline: 2.0778x; 2.0778x over previous
//
#include <hip/hip_runtime.h>
#include <math.h>

#define B_   8
#define N_   4096
#define DIM_ 768
#define H_   12
#define D_   64

typedef unsigned short ushort_t;
typedef unsigned int uint_t;
typedef __attribute__((ext_vector_type(8))) short short8;
typedef __attribute__((ext_vector_type(4))) float f32x4;

// ---------------------------------------------------------------------------
// helpers
// ---------------------------------------------------------------------------
__device__ __forceinline__ float gelu_exact(float z) {
  return 0.5f * z * (1.f + erff(z * 0.70710678118654752440f));
}

__device__ __forceinline__ ushort_t f2bf(float f) {
  union { float f; unsigned u; } x; x.f = f;
  unsigned r = x.u + 0x7FFFu + ((x.u >> 16) & 1u);   // RNE
  return (ushort_t)(r >> 16);
}

__device__ __forceinline__ float bf2f(ushort_t h) {
  union { unsigned u; float f; } x; x.u = ((unsigned)h) << 16;
  return x.f;
}

__device__ __forceinline__ void gl_lds16(const ushort_t* g, ushort_t* l) {
  __builtin_amdgcn_global_load_lds(
      (const __attribute__((address_space(1))) void*)g,
      (__attribute__((address_space(3))) void*)l, 16, 0, 0);
}

// ---------------------------------------------------------------------------
// 768x768 fp32 -> bf16 transposed copy (dst[n][k] = src[k][n])
// ---------------------------------------------------------------------------
__global__ __launch_bounds__(256) void transpose_w_bf16(
    const float* __restrict__ src, ushort_t* __restrict__ dst)
{
  __shared__ float t[32][33];
  const int lx = threadIdx.x & 31, ly = threadIdx.x >> 5;
  const int bx = blockIdx.x * 32;
  const int by = blockIdx.y * 32;
  #pragma unroll
  for (int j = 0; j < 32; j += 8)
    t[ly + j][lx] = src[(size_t)(by + ly + j) * 768 + bx + lx];
  __syncthreads();
  #pragma unroll
  for (int j = 0; j < 32; j += 8)
    dst[(size_t)(bx + ly + j) * 768 + by + lx] = f2bf(t[lx][ly + j]);
}

// 6x 64x64 transpose to bf16: dst[m][c][d] = src_m[d][c]; m<3 pool, else exp
__global__ __launch_bounds__(256) void transpose64_bf16(
    const float* __restrict__ pW, const float* __restrict__ eW,
    ushort_t* __restrict__ dst)
{
  const int m = blockIdx.x;
  const float* src = (m < 3) ? (pW + m * 4096) : (eW + (m - 3) * 4096);
  ushort_t* o = dst + m * 4096;
  for (int i = threadIdx.x; i < 4096; i += 256) {
    const int r = i >> 6, c = i & 63;
    o[c * 64 + r] = f2bf(src[r * 64 + c]);
  }
}

__global__ __launch_bounds__(256) void conv_f32_bf16(
    const float* __restrict__ src, ushort_t* __restrict__ dst)
{
  const int i = blockIdx.x * 256 + threadIdx.x;
  float4 f = ((const float4*)src)[i];
  ushort4 o;
  o.x = f2bf(f.x); o.y = f2bf(f.y); o.z = f2bf(f.z); o.w = f2bf(f.w);
  ((ushort4*)dst)[i] = o;
}

// ---------------------------------------------------------------------------
// bf16 MFMA GEMM mainloop: 128x128 tile, BK=32, 4 waves 2x2, 4x4 16x16 each
// ---------------------------------------------------------------------------
#define GEMM_MAINLOOP(A, Bt, K)                                               \
  __shared__ ushort_t As[128 * 32];                                           \
  __shared__ ushort_t Bs[128 * 32];                                           \
  const int tid = threadIdx.x;                                                \
  const int row0 = blockIdx.y * 128;                                          \
  const int col0 = blockIdx.x * 128;                                          \
  const int sr = tid >> 2;                                                    \
  const int sk = (tid & 3) * 8;                                               \
  const ushort_t* Ag0 = (A) + (size_t)(row0 + sr) * (K) + sk;                 \
  const ushort_t* Ag1 = Ag0 + (size_t)64 * (K);                               \
  const ushort_t* Bg0 = (Bt) + (size_t)(col0 + sr) * (K) + sk;                \
  const ushort_t* Bg1 = Bg0 + (size_t)64 * (K);                               \
  ushort_t* Asw = As + (tid >> 6) * 512;                                      \
  ushort_t* Bsw = Bs + (tid >> 6) * 512;                                      \
  const int w = tid >> 6, lane = tid & 63;                                    \
  const int wm = w >> 1, wn = w & 1;                                          \
  const int qd = lane >> 4, l15 = lane & 15;                                  \
  const int aoff = (wm * 64 + l15) * 32 + qd * 8;                             \
  const int boff = (wn * 64 + l15) * 32 + qd * 8;                             \
  f32x4 acc[4][4] = {};                                                       \
  for (int k0 = 0; k0 < (K); k0 += 32) {                                      \
    __syncthreads();                                                          \
    gl_lds16(Ag0 + k0, Asw);                                                  \
    gl_lds16(Ag1 + k0, Asw + 2048);                                           \
    gl_lds16(Bg0 + k0, Bsw);                                                  \
    gl_lds16(Bg1 + k0, Bsw + 2048);                                           \
    __syncthreads();                                                          \
    short8 af[4], bfr[4];                                                     \
    _Pragma("unroll")                                                         \
    for (int mt = 0; mt < 4; ++mt) af[mt] = *(const short8*)&As[aoff + mt * 512]; \
    _Pragma("unroll")                                                         \
    for (int nt = 0; nt < 4; ++nt) bfr[nt] = *(const short8*)&Bs[boff + nt * 512]; \
    _Pragma("unroll")                                                         \
    for (int mt = 0; mt < 4; ++mt)                                            \
      _Pragma("unroll")                                                       \
      for (int nt = 0; nt < 4; ++nt)                                          \
        acc[mt][nt] = __builtin_amdgcn_mfma_f32_16x16x32_bf16(                \
            af[mt], bfr[nt], acc[mt][nt], 0, 0, 0);                           \
  }

// QKV (batched over NB batches via row index): q bf16 elu+1, k bf16 elu+1.
// v columns are pooled (mean of 8 tokens) in-register and written straight to
// vc f32 [b][12][512][64]. grid (18, NB*32)
__global__ __launch_bounds__(256) void gemm_qkv(
    const ushort_t* __restrict__ A, const ushort_t* __restrict__ Bt,
    ushort_t* __restrict__ qo, ushort_t* __restrict__ ko, float* __restrict__ vco)
{
  GEMM_MAINLOOP(A, Bt, 768)
  const int sel = col0 / 768;
  const int colbase = (col0 % 768) + wn * 64;
  if (sel < 2) {
    ushort_t* o = (sel == 0) ? qo : ko;
    #pragma unroll
    for (int mt = 0; mt < 4; ++mt) {
      #pragma unroll
      for (int nt = 0; nt < 4; ++nt) {
        const int cg = colbase + nt * 16 + l15;
        #pragma unroll
        for (int r = 0; r < 4; ++r) {
          const int rg = row0 + wm * 64 + mt * 16 + qd * 4 + r;
          const float vv = acc[mt][nt][r];
          const float e = (vv > 0.f) ? vv + 1.f : expf(vv);
          o[(size_t)rg * 768 + cg] = f2bf(e);
        }
      }
    }
  } else {
    // v-path: pool mean over 8 consecutive tokens, write vc directly.
    const int b = row0 >> 12;                       // batch within chunk
    const int hh = colbase >> 6;                    // head 0..11
    const int n8base = ((row0 & 4095) >> 3) + wm * 8 + (qd >> 1);
    #pragma unroll
    for (int mt = 0; mt < 4; ++mt) {
      #pragma unroll
      for (int nt = 0; nt < 4; ++nt) {
        float s = acc[mt][nt][0] + acc[mt][nt][1] + acc[mt][nt][2] + acc[mt][nt][3];
        s += __shfl_xor(s, 16, 64);                 // combine quad pairs -> 8 rows
        if (!(qd & 1)) {
          const int n8 = n8base + mt * 2;
          const int d = nt * 16 + l15;
          vco[(((size_t)b * 12 + hh) * 512 + n8) * 64 + d] = 0.125f * s;
        }
      }
    }
  }
}

// Output GEMM + bias. grid (6, NB*32)
__global__ __launch_bounds__(256) void gemm_out(
    const ushort_t* __restrict__ A, const ushort_t* __restrict__ Bt,
    const float* __restrict__ bo, float* __restrict__ C)
{
  GEMM_MAINLOOP(A, Bt, 768)
  #pragma unroll
  for (int mt = 0; mt < 4; ++mt) {
    #pragma unroll
    for (int nt = 0; nt < 4; ++nt) {
      const int cg = col0 + wn * 64 + nt * 16 + l15;
      #pragma unroll
      for (int r = 0; r < 4; ++r) {
        const int rg = row0 + wm * 64 + mt * 16 + qd * 4 + r;
        C[(size_t)rg * 768 + cg] = acc[mt][nt][r] + bo[cg];
      }
    }
  }
}

// ---------------------------------------------------------------------------
// MFMA pool stage: t = mean(in[2n],in[2n+1]); out = gelu(LN(t@W+b)*g+be)
// 128 out-tokens/block, 4 waves. grid (n_out/128, 12, NB)
// in bf16 addressed in[bb*in_bs + h*h_stride + n*ts + d]; out [bb][h][n_out][64]
// ---------------------------------------------------------------------------
__global__ __launch_bounds__(256) void pool_mfma(
    const ushort_t* __restrict__ in, ushort_t* __restrict__ out,
    int n_out, long h_stride, int ts, long in_bs, long out_bs,
    const ushort_t* __restrict__ Wt, const float* __restrict__ bias,
    const float* __restrict__ g, const float* __restrict__ be)
{
  __shared__ ushort_t Wl[64 * 72];    // W^T rows padded to 72
  __shared__ ushort_t tl[128 * 72];   // pooled input, A-layout rows
  const int tid = threadIdx.x;
  const int h = blockIdx.y;
  const int bb = blockIdx.z;
  const int row0 = blockIdx.x * 128;
  in  += (size_t)bb * in_bs;
  out += (size_t)bb * out_bs;

  {
    const uint_t* ws = (const uint_t*)Wt;
    for (int i = tid; i < 2048; i += 256) {
      const int r = i >> 5, c = i & 31;
      ((uint_t*)(Wl + r * 72))[c] = ws[i];
    }
  }
  #pragma unroll
  for (int j = 0; j < 4; ++j) {
    const int idx = j * 256 + tid;
    const int rl = idx >> 3, ch = idx & 7;
    const ushort_t* p = in + (size_t)h * h_stride + (size_t)(2 * (row0 + rl)) * ts + ch * 8;
    short8 a = *(const short8*)p;
    short8 b2 = *(const short8*)(p + ts);
    short8 o;
    #pragma unroll
    for (int e = 0; e < 8; ++e)
      o[e] = (short)f2bf(0.5f * (bf2f((ushort_t)a[e]) + bf2f((ushort_t)b2[e])));
    *(short8*)&tl[rl * 72 + ch * 8] = o;
  }
  __syncthreads();

  const int w = tid >> 6, lane = tid & 63;
  const int quad = lane >> 4, l15 = lane & 15;

  float bv[4], gv[4], bev[4];
  #pragma unroll
  for (int nt = 0; nt < 4; ++nt) {
    const int c = nt * 16 + l15;
    bv[nt] = bias[c]; gv[nt] = g[c]; bev[nt] = be[c];
  }
  f32x4 a2[2][4];
  #pragma unroll
  for (int mt = 0; mt < 2; ++mt)
    #pragma unroll
    for (int nt = 0; nt < 4; ++nt)
      a2[mt][nt] = f32x4{bv[nt], bv[nt], bv[nt], bv[nt]};

  #pragma unroll
  for (int ks = 0; ks < 2; ++ks) {
    short8 af[2], bfr[4];
    #pragma unroll
    for (int mt = 0; mt < 2; ++mt)
      af[mt] = *(const short8*)&tl[(w * 32 + mt * 16 + l15) * 72 + ks * 32 + quad * 8];
    #pragma unroll
    for (int nt = 0; nt < 4; ++nt)
      bfr[nt] = *(const short8*)&Wl[(nt * 16 + l15) * 72 + ks * 32 + quad * 8];
    #pragma unroll
    for (int mt = 0; mt < 2; ++mt)
      #pragma unroll
      for (int nt = 0; nt < 4; ++nt)
        a2[mt][nt] = __builtin_amdgcn_mfma_f32_16x16x32_bf16(af[mt], bfr[nt], a2[mt][nt], 0, 0, 0);
  }

  #pragma unroll
  for (int mt = 0; mt < 2; ++mt)
    #pragma unroll
    for (int r = 0; r < 4; ++r) {
      float sum = a2[mt][0][r] + a2[mt][1][r] + a2[mt][2][r] + a2[mt][3][r];
      #pragma unroll
      for (int m = 1; m < 16; m <<= 1) sum += __shfl_xor(sum, m, 64);
      const float mu = sum * 0.015625f;
      float dv[4], var = 0.f;
      #pragma unroll
      for (int nt = 0; nt < 4; ++nt) { dv[nt] = a2[mt][nt][r] - mu; var += dv[nt] * dv[nt]; }
      #pragma unroll
      for (int m = 1; m < 16; m <<= 1) var += __shfl_xor(var, m, 64);
      const float rstd = rsqrtf(var * 0.015625f + 1e-5f);
      const int rg = row0 + w * 32 + mt * 16 + quad * 4 + r;
      #pragma unroll
      for (int nt = 0; nt < 4; ++nt) {
        const float z = dv[nt] * rstd * gv[nt] + bev[nt];
        out[((size_t)h * n_out + rg) * 64 + nt * 16 + l15] = f2bf(gelu_exact(z));
      }
    }
}

// ---------------------------------------------------------------------------
// kv partials over 32-token chunks: kc bf16, vc f32. grid (12, 16, NB)
// ---------------------------------------------------------------------------
__global__ __launch_bounds__(256) void kv_part_kernel(
    const ushort_t* __restrict__ kc, const float* __restrict__ vc,
    float* __restrict__ kvp, float* __restrict__ ksp)
{
  __shared__ float ks[32 * 64];
  __shared__ float vs[32 * 64];
  const int tid = threadIdx.x;
  const int h = blockIdx.x;
  const int c = blockIdx.y;
  const int bb = blockIdx.z;
  kc  += (size_t)bb * 393216;
  vc  += (size_t)bb * 393216;
  kvp += (size_t)bb * 786432;
  ksp += (size_t)bb * 12288;
  const ushort_t* kp = kc + ((size_t)h * 512 + c * 32) * 64;
  const float* vp = vc + ((size_t)h * 512 + c * 32) * 64;
  #pragma unroll
  for (int i = 0; i < 2; ++i) {
    ushort4 u = ((const ushort4*)kp)[tid + 256 * i];
    float4 f; f.x = bf2f(u.x); f.y = bf2f(u.y); f.z = bf2f(u.z); f.w = bf2f(u.w);
    ((float4*)ks)[tid + 256 * i] = f;
    ((float4*)vs)[tid + 256 * i] = ((const float4*)vp)[tid + 256 * i];
  }
  __syncthreads();

  const int e = tid & 63;
  const int dg = tid >> 6;
  float acc[16] = {};
  float accs = 0.f;
  for (int nn = 0; nn < 32; ++nn) {
    const float vv = vs[nn * 64 + e];
    #pragma unroll
    for (int j = 0; j < 16; ++j)
      acc[j] += ks[nn * 64 + dg * 16 + j] * vv;
    if (tid < 64) accs += ks[nn * 64 + tid];
  }
  float* o = kvp + ((size_t)h * 16 + c) * 4096;
  #pragma unroll
  for (int j = 0; j < 16; ++j)
    o[(dg * 16 + j) * 64 + e] = acc[j];
  if (tid < 64) ksp[(h * 16 + c) * 64 + tid] = accs;
}

// reduce partials -> kvxT bf16 [bb][h][80][64]: rows 0..63 = kv^T (e,d),
// row 64 = ksum, rows 65..79 = 0. grid (240, NB).
__global__ __launch_bounds__(256) void kv_reduce_t(
    const float* __restrict__ kvp, const float* __restrict__ ksp,
    ushort_t* __restrict__ kvxT)
{
  const int bb = blockIdx.y;
  kvp  += (size_t)bb * 786432;
  ksp  += (size_t)bb * 12288;
  kvxT += (size_t)bb * 61440;
  const int idx = blockIdx.x * 256 + threadIdx.x;   // < 61440
  const int h = idx / 5120;
  const int rem = idx - h * 5120;
  const int er = rem >> 6, d = rem & 63;
  const float scale = 0.044194173824159216f;  // 1/sqrt(512)
  float val = 0.f;
  if (er < 64) {
    float s = 0.f;
    #pragma unroll
    for (int c = 0; c < 16; ++c) s += kvp[((size_t)h * 16 + c) * 4096 + d * 64 + er];
    val = s * scale;
  } else if (er == 64) {
    float s = 0.f;
    #pragma unroll
    for (int c = 0; c < 16; ++c) s += ksp[(h * 16 + c) * 64 + d];
    val = s * scale;
  }
  kvxT[idx] = f2bf(val);
}

// ---------------------------------------------------------------------------
// Fused MFMA attention-apply + 3 expansion MLPs.
// grid (32, 12, NB): 128 tokens x 1 head per block. Writes bf16 (n,768).
// ---------------------------------------------------------------------------
__global__ __launch_bounds__(256) void attn_exp_mfma(
    const ushort_t* __restrict__ q16, const ushort_t* __restrict__ kvxT,
    const ushort_t* __restrict__ eWt,
    const float* __restrict__ eb, const float* __restrict__ eg,
    const float* __restrict__ ebe, ushort_t* __restrict__ out16)
{
  __shared__ ushort_t kvl[80 * 72];
  __shared__ ushort_t Wl[3 * 64 * 72];
  __shared__ ushort_t tl[128 * 72];
  const int tid = threadIdx.x;
  const int h = blockIdx.y;
  const int bb = blockIdx.z;
  const int row0 = blockIdx.x * 128;
  q16   += (size_t)bb * 3145728;
  out16 += (size_t)bb * 3145728;
  kvxT  += (size_t)bb * 61440;

  {
    const uint_t* src = (const uint_t*)(kvxT + (size_t)h * 5120);
    for (int i = tid; i < 2560; i += 256) {
      const int r = i >> 5, c = i & 31;
      ((uint_t*)(kvl + r * 72))[c] = src[i];
    }
    const uint_t* ws = (const uint_t*)eWt;
    for (int i = tid; i < 6144; i += 256) {
      const int s = i >> 11, rem = i & 2047, r = rem >> 5, c = rem & 31;
      ((uint_t*)(Wl + (s * 64 + r) * 72))[c] = ws[i];
    }
  }
  __syncthreads();

  const int w = tid >> 6, lane = tid & 63;
  const int quad = lane >> 4, l15 = lane & 15;

  // attention matmul incl. denominator column
  f32x4 acc[2][5] = {};
  #pragma unroll
  for (int ks = 0; ks < 2; ++ks) {
    short8 af[2], bfr[5];
    #pragma unroll
    for (int mt = 0; mt < 2; ++mt) {
      const int rg = row0 + w * 32 + mt * 16 + l15;
      af[mt] = *(const short8*)(q16 + (size_t)rg * 768 + h * 64 + ks * 32 + quad * 8);
    }
    #pragma unroll
    for (int nt = 0; nt < 5; ++nt)
      bfr[nt] = *(const short8*)&kvl[(nt * 16 + l15) * 72 + ks * 32 + quad * 8];
    #pragma unroll
    for (int mt = 0; mt < 2; ++mt)
      #pragma unroll
      for (int nt = 0; nt < 5; ++nt)
        acc[mt][nt] = __builtin_amdgcn_mfma_f32_16x16x32_bf16(af[mt], bfr[nt], acc[mt][nt], 0, 0, 0);
  }

  float t[2][4][4];
  #pragma unroll
  for (int mt = 0; mt < 2; ++mt)
    #pragma unroll
    for (int r = 0; r < 4; ++r) {
      const float den = __shfl(acc[mt][4][r], lane & 48, 64) + 1e-6f;
      const float inv = 1.f / den;
      #pragma unroll
      for (int nt = 0; nt < 4; ++nt)
        t[mt][nt][r] = acc[mt][nt][r] * inv;
    }

  // 3 expansion stages (s = 2, 1, 0)
  for (int s = 2; s >= 0; --s) {
    __syncthreads();
    #pragma unroll
    for (int mt = 0; mt < 2; ++mt)
      #pragma unroll
      for (int nt = 0; nt < 4; ++nt)
        #pragma unroll
        for (int r = 0; r < 4; ++r)
          tl[(w * 32 + mt * 16 + quad * 4 + r) * 72 + nt * 16 + l15] = f2bf(t[mt][nt][r]);
    __syncthreads();

    float bv[4], gv[4], bev[4];
    #pragma unroll
    for (int nt = 0; nt < 4; ++nt) {
      const int c = s * 64 + nt * 16 + l15;
      bv[nt] = eb[c]; gv[nt] = eg[c]; bev[nt] = ebe[c];
    }
    f32x4 a2[2][4];
    #pragma unroll
    for (int mt = 0; mt < 2; ++mt)
      #pragma unroll
      for (int nt = 0; nt < 4; ++nt)
        a2[mt][nt] = f32x4{bv[nt], bv[nt], bv[nt], bv[nt]};

    #pragma unroll
    for (int ks = 0; ks < 2; ++ks) {
      short8 af[2], bfr[4];
      #pragma unroll
      for (int mt = 0; mt < 2; ++mt)
        af[mt] = *(const short8*)&tl[(w * 32 + mt * 16 + l15) * 72 + ks * 32 + quad * 8];
      #pragma unroll
      for (int nt = 0; nt < 4; ++nt)
        bfr[nt] = *(const short8*)&Wl[(s * 64 + nt * 16 + l15) * 72 + ks * 32 + quad * 8];
      #pragma unroll
      for (int mt = 0; mt < 2; ++mt)
        #pragma unroll
        for (int nt = 0; nt < 4; ++nt)
          a2[mt][nt] = __builtin_amdgcn_mfma_f32_16x16x32_bf16(af[mt], bfr[nt], a2[mt][nt], 0, 0, 0);
    }

    #pragma unroll
    for (int mt = 0; mt < 2; ++mt)
      #pragma unroll
      for (int r = 0; r < 4; ++r) {
        float sum = a2[mt][0][r] + a2[mt][1][r] + a2[mt][2][r] + a2[mt][3][r];
        #pragma unroll
        for (int m = 1; m < 16; m <<= 1) sum += __shfl_xor(sum, m, 64);
        const float mu = sum * 0.015625f;
        float dv[4], var = 0.f;
        #pragma unroll
        for (int nt = 0; nt < 4; ++nt) { dv[nt] = a2[mt][nt][r] - mu; var += dv[nt] * dv[nt]; }
        #pragma unroll
        for (int m = 1; m < 16; m <<= 1) var += __shfl_xor(var, m, 64);
        const float rstd = rsqrtf(var * 0.015625f + 1e-5f);
        #pragma unroll
        for (int nt = 0; nt < 4; ++nt) {
          const float z = dv[nt] * rstd * gv[nt] + bev[nt];
          t[mt][nt][r] = gelu_exact(z);
        }
      }
  }

  #pragma unroll
  for (int mt = 0; mt < 2; ++mt)
    #pragma unroll
    for (int nt = 0; nt < 4; ++nt)
      #pragma unroll
      for (int r = 0; r < 4; ++r) {
        const int rg = row0 + w * 32 + mt * 16 + quad * 4 + r;
        out16[(size_t)rg * 768 + h * 64 + nt * 16 + l15] = f2bf(t[mt][nt][r]);
      }
}

// ---------------------------------------------------------------------------
// launch
// ---------------------------------------------------------------------------
extern "C" void kernel_launch(void* const* d_in, const int* in_sizes, int n_in,
                              void* d_out, int out_size, void* d_ws, size_t ws_size,
                              hipStream_t stream)
{
  const float* x   = (const float*)d_in[0];
  const float* Wq  = (const float*)d_in[1];
  const float* Wk  = (const float*)d_in[2];
  const float* Wv  = (const float*)d_in[3];
  const float* pW  = (const float*)d_in[4];
  const float* pb  = (const float*)d_in[5];
  const float* pg  = (const float*)d_in[6];
  const float* pbe = (const float*)d_in[7];
  const float* eW  = (const float*)d_in[8];
  const float* eb  = (const float*)d_in[9];
  const float* eg  = (const float*)d_in[10];
  const float* ebe = (const float*)d_in[11];
  const float* Wo  = (const float*)d_in[12];
  const float* bo  = (const float*)d_in[13];
  float* outp = (float*)d_out;

  // ---- workspace: fixed weight area + NB-batch chunk area ----
  unsigned char* wsb = (unsigned char*)d_ws;
  ushort_t* WqkvT = (ushort_t*)(wsb + 0);              // 3,538,944
  ushort_t* WoT   = (ushort_t*)(wsb + 3538944);        // 1,179,648
  ushort_t* Wt6   = (ushort_t*)(wsb + 4718592);        //    49,152
  const size_t CB   = 4767744;                         // chunk base
  const size_t PERB = 26075136;                        // bytes per batch

  int NB;
  if      (ws_size >= CB + 8 * PERB) NB = 8;
  else if (ws_size >= CB + 4 * PERB) NB = 4;
  else if (ws_size >= CB + 2 * PERB) NB = 2;
  else if (ws_size >= CB + 1 * PERB) NB = 1;
  else return;

  unsigned char* cb = wsb + CB;
  ushort_t* xb16 = (ushort_t*)(cb);                                  // NB*6,291,456
  ushort_t* q16  = (ushort_t*)(cb + (size_t)NB *  6291456);          // NB*6,291,456
  ushort_t* k16  = (ushort_t*)(cb + (size_t)NB * 12582912);          // NB*6,291,456
  float*    vc   = (float*)   (cb + (size_t)NB * 18874368);          // NB*1,572,864
  ushort_t* kc_a = (ushort_t*)(cb + (size_t)NB * 20447232);          // NB*3,145,728
  ushort_t* kc_b = (ushort_t*)(cb + (size_t)NB * 23592960);          // NB*1,572,864
  ushort_t* kc_c = (ushort_t*)(cb + (size_t)NB * 25165824);          // NB*  786,432
  ushort_t* kvxT = (ushort_t*)(cb + (size_t)NB * 25952256);          // NB*  122,880
  // aliases: kvp/ksp live in k16's space (k16 dead after pool stage 1);
  //          ao16 lives in xb16's space (xb16 dead after gemm_qkv).
  float* kvp = (float*)k16;
  float* ksp = (float*)((unsigned char*)k16 + (size_t)NB * 3145728);
  ushort_t* ao16 = xb16;

  const ushort_t* pWt = Wt6;
  const ushort_t* eWt = Wt6 + 3 * 4096;
  const size_t SB = (size_t)N_ * DIM_;

  transpose_w_bf16<<<dim3(24, 24), 256, 0, stream>>>(Wq, WqkvT);
  transpose_w_bf16<<<dim3(24, 24), 256, 0, stream>>>(Wk, WqkvT + 768 * 768);
  transpose_w_bf16<<<dim3(24, 24), 256, 0, stream>>>(Wv, WqkvT + 2 * 768 * 768);
  transpose_w_bf16<<<dim3(24, 24), 256, 0, stream>>>(Wo, WoT);
  transpose64_bf16<<<6, 256, 0, stream>>>(pW, eW, Wt6);

  for (int b0 = 0; b0 < B_; b0 += NB) {
    const float* xc = x + (size_t)b0 * SB;
    float* oc = outp + (size_t)b0 * SB;

    conv_f32_bf16<<<NB * 3072, 256, 0, stream>>>(xc, xb16);
    gemm_qkv<<<dim3(18, NB * 32), 256, 0, stream>>>(xb16, WqkvT, q16, k16, vc);

    // k-path pooling (MFMA), output [bb][h][n][64] bf16
    pool_mfma<<<dim3(16, 12, NB), 256, 0, stream>>>(k16, kc_a, 2048, 64L, 768,
        3145728L, 1572864L, pWt, pb, pg, pbe);
    pool_mfma<<<dim3(8, 12, NB), 256, 0, stream>>>(kc_a, kc_b, 1024, 131072L, 64,
        1572864L, 786432L, pWt + 4096, pb + 64, pg + 64, pbe + 64);
    pool_mfma<<<dim3(4, 12, NB), 256, 0, stream>>>(kc_b, kc_c, 512, 65536L, 64,
        786432L, 393216L, pWt + 8192, pb + 128, pg + 128, pbe + 128);

    kv_part_kernel<<<dim3(12, 16, NB), 256, 0, stream>>>(kc_c, vc, kvp, ksp);
    kv_reduce_t<<<dim3(240, NB), 256, 0, stream>>>(kvp, ksp, kvxT);

    attn_exp_mfma<<<dim3(32, 12, NB), 256, 0, stream>>>(q16, kvxT, eWt,
                                                        eb, eg, ebe, ao16);

    gemm_out<<<dim3(6, NB * 32), 256, 0, stream>>>(ao16, WoT, bo, oc);
  }
}

// Round 2
// 697.998 us; speedup vs baseline: 2.0998x; 1.0106x over previous
//
#include <hip/hip_runtime.h>
#include <math.h>

#define B_   8
#define N_   4096
#define DIM_ 768
#define H_   12
#define D_   64

typedef unsigned short ushort_t;
typedef unsigned int uint_t;
typedef __attribute__((ext_vector_type(8))) short short8;
typedef __attribute__((ext_vector_type(4))) float f32x4;

// ---------------------------------------------------------------------------
// helpers
// ---------------------------------------------------------------------------
__device__ __forceinline__ float gelu_exact(float z) {
  return 0.5f * z * (1.f + erff(z * 0.70710678118654752440f));
}

__device__ __forceinline__ ushort_t f2bf(float f) {
  union { float f; unsigned u; } x; x.f = f;
  unsigned r = x.u + 0x7FFFu + ((x.u >> 16) & 1u);   // RNE
  return (ushort_t)(r >> 16);
}

__device__ __forceinline__ float bf2f(ushort_t h) {
  union { unsigned u; float f; } x; x.u = ((unsigned)h) << 16;
  return x.f;
}

__device__ __forceinline__ void gl_lds16(const ushort_t* g, ushort_t* l) {
  __builtin_amdgcn_global_load_lds(
      (const __attribute__((address_space(1))) void*)g,
      (__attribute__((address_space(3))) void*)l, 16, 0, 0);
}

// ---------------------------------------------------------------------------
// 768x768 fp32 -> bf16 transposed copy (dst[n][k] = src[k][n])
// ---------------------------------------------------------------------------
__global__ __launch_bounds__(256) void transpose_w_bf16(
    const float* __restrict__ src, ushort_t* __restrict__ dst)
{
  __shared__ float t[32][33];
  const int lx = threadIdx.x & 31, ly = threadIdx.x >> 5;
  const int bx = blockIdx.x * 32;
  const int by = blockIdx.y * 32;
  #pragma unroll
  for (int j = 0; j < 32; j += 8)
    t[ly + j][lx] = src[(size_t)(by + ly + j) * 768 + bx + lx];
  __syncthreads();
  #pragma unroll
  for (int j = 0; j < 32; j += 8)
    dst[(size_t)(bx + ly + j) * 768 + by + lx] = f2bf(t[lx][ly + j]);
}

// 6x 64x64 transpose to bf16: dst[m][c][d] = src_m[d][c]; m<3 pool, else exp
__global__ __launch_bounds__(256) void transpose64_bf16(
    const float* __restrict__ pW, const float* __restrict__ eW,
    ushort_t* __restrict__ dst)
{
  const int m = blockIdx.x;
  const float* src = (m < 3) ? (pW + m * 4096) : (eW + (m - 3) * 4096);
  ushort_t* o = dst + m * 4096;
  for (int i = threadIdx.x; i < 4096; i += 256) {
    const int r = i >> 6, c = i & 63;
    o[c * 64 + r] = f2bf(src[r * 64 + c]);
  }
}

__global__ __launch_bounds__(256) void conv_f32_bf16(
    const float* __restrict__ src, ushort_t* __restrict__ dst)
{
  const int i = blockIdx.x * 256 + threadIdx.x;
  float4 f = ((const float4*)src)[i];
  ushort4 o;
  o.x = f2bf(f.x); o.y = f2bf(f.y); o.z = f2bf(f.z); o.w = f2bf(f.w);
  ((ushort4*)dst)[i] = o;
}

// ---------------------------------------------------------------------------
// bf16 MFMA GEMM mainloop: 128x128 tile, BK=32, 4 waves 2x2, 4x4 16x16 each.
// Double-buffered LDS (T3 minimum 2-phase: stage k+1 before compute k) +
// bijective XCD chunk swizzle (T1) so each XCD owns contiguous row-tiles.
// ---------------------------------------------------------------------------
#define GEMM_STAGE(kk, As_, Bs_)                                              \
    gl_lds16(Ag0 + (kk), (As_) + stoff_);                                     \
    gl_lds16(Ag1 + (kk), (As_) + stoff_ + 2048);                              \
    gl_lds16(Bg0 + (kk), (Bs_) + stoff_);                                     \
    gl_lds16(Bg1 + (kk), (Bs_) + stoff_ + 2048);

#define GEMM_COMPUTE(As_, Bs_)                                                \
  { short8 af[4], bfr[4];                                                     \
    _Pragma("unroll")                                                         \
    for (int mt = 0; mt < 4; ++mt) af[mt] = *(const short8*)&(As_)[aoff + mt * 512]; \
    _Pragma("unroll")                                                         \
    for (int nt = 0; nt < 4; ++nt) bfr[nt] = *(const short8*)&(Bs_)[boff + nt * 512]; \
    _Pragma("unroll")                                                         \
    for (int mt = 0; mt < 4; ++mt)                                            \
      _Pragma("unroll")                                                       \
      for (int nt = 0; nt < 4; ++nt)                                          \
        acc[mt][nt] = __builtin_amdgcn_mfma_f32_16x16x32_bf16(                \
            af[mt], bfr[nt], acc[mt][nt], 0, 0, 0); }

#define GEMM_MAINLOOP(A, Bt, K)                                               \
  __shared__ ushort_t As0[128 * 32];                                          \
  __shared__ ushort_t As1[128 * 32];                                          \
  __shared__ ushort_t Bs0[128 * 32];                                          \
  __shared__ ushort_t Bs1[128 * 32];                                          \
  const int tid = threadIdx.x;                                                \
  const int nwg_ = (int)(gridDim.x * gridDim.y);                              \
  const int wgid0_ = (int)(blockIdx.y * gridDim.x + blockIdx.x);              \
  const int wgid_ = (wgid0_ & 7) * (nwg_ >> 3) + (wgid0_ >> 3);               \
  const int row0 = (wgid_ / (int)gridDim.x) * 128;                            \
  const int col0 = (wgid_ % (int)gridDim.x) * 128;                            \
  const int sr = tid >> 2;                                                    \
  const int sk = (tid & 3) * 8;                                               \
  const ushort_t* Ag0 = (A) + (size_t)(row0 + sr) * (K) + sk;                 \
  const ushort_t* Ag1 = Ag0 + (size_t)64 * (K);                               \
  const ushort_t* Bg0 = (Bt) + (size_t)(col0 + sr) * (K) + sk;                \
  const ushort_t* Bg1 = Bg0 + (size_t)64 * (K);                               \
  const int stoff_ = (tid >> 6) * 512;                                        \
  const int w = tid >> 6, lane = tid & 63;                                    \
  const int wm = w >> 1, wn = w & 1;                                          \
  const int qd = lane >> 4, l15 = lane & 15;                                  \
  const int aoff = (wm * 64 + l15) * 32 + qd * 8;                             \
  const int boff = (wn * 64 + l15) * 32 + qd * 8;                             \
  f32x4 acc[4][4] = {};                                                       \
  GEMM_STAGE(0, As0, Bs0)                                                     \
  for (int k0 = 0; k0 < (K); k0 += 64) {                                      \
    __syncthreads();                                                          \
    GEMM_STAGE(k0 + 32, As1, Bs1)                                             \
    GEMM_COMPUTE(As0, Bs0)                                                    \
    __syncthreads();                                                          \
    if (k0 + 64 < (K)) { GEMM_STAGE(k0 + 64, As0, Bs0) }                      \
    GEMM_COMPUTE(As1, Bs1)                                                    \
  }

// QKV (batched over NB batches via row index): q bf16 elu+1, k bf16 elu+1.
// v columns are pooled (mean of 8 tokens) in-register and written straight to
// vc f32 [b][12][512][64]. grid (18, NB*32)
__global__ __launch_bounds__(256) void gemm_qkv(
    const ushort_t* __restrict__ A, const ushort_t* __restrict__ Bt,
    ushort_t* __restrict__ qo, ushort_t* __restrict__ ko, float* __restrict__ vco)
{
  GEMM_MAINLOOP(A, Bt, 768)
  const int sel = col0 / 768;
  const int colbase = (col0 % 768) + wn * 64;
  if (sel < 2) {
    ushort_t* o = (sel == 0) ? qo : ko;
    #pragma unroll
    for (int mt = 0; mt < 4; ++mt) {
      #pragma unroll
      for (int nt = 0; nt < 4; ++nt) {
        const int cg = colbase + nt * 16 + l15;
        #pragma unroll
        for (int r = 0; r < 4; ++r) {
          const int rg = row0 + wm * 64 + mt * 16 + qd * 4 + r;
          const float vv = acc[mt][nt][r];
          const float e = (vv > 0.f) ? vv + 1.f : expf(vv);
          o[(size_t)rg * 768 + cg] = f2bf(e);
        }
      }
    }
  } else {
    // v-path: pool mean over 8 consecutive tokens, write vc directly.
    const int b = row0 >> 12;                       // batch within chunk
    const int hh = colbase >> 6;                    // head 0..11
    const int n8base = ((row0 & 4095) >> 3) + wm * 8 + (qd >> 1);
    #pragma unroll
    for (int mt = 0; mt < 4; ++mt) {
      #pragma unroll
      for (int nt = 0; nt < 4; ++nt) {
        float s = acc[mt][nt][0] + acc[mt][nt][1] + acc[mt][nt][2] + acc[mt][nt][3];
        s += __shfl_xor(s, 16, 64);                 // combine quad pairs -> 8 rows
        if (!(qd & 1)) {
          const int n8 = n8base + mt * 2;
          const int d = nt * 16 + l15;
          vco[(((size_t)b * 12 + hh) * 512 + n8) * 64 + d] = 0.125f * s;
        }
      }
    }
  }
}

// Output GEMM + bias. grid (6, NB*32)
__global__ __launch_bounds__(256) void gemm_out(
    const ushort_t* __restrict__ A, const ushort_t* __restrict__ Bt,
    const float* __restrict__ bo, float* __restrict__ C)
{
  GEMM_MAINLOOP(A, Bt, 768)
  #pragma unroll
  for (int mt = 0; mt < 4; ++mt) {
    #pragma unroll
    for (int nt = 0; nt < 4; ++nt) {
      const int cg = col0 + wn * 64 + nt * 16 + l15;
      #pragma unroll
      for (int r = 0; r < 4; ++r) {
        const int rg = row0 + wm * 64 + mt * 16 + qd * 4 + r;
        C[(size_t)rg * 768 + cg] = acc[mt][nt][r] + bo[cg];
      }
    }
  }
}

// ---------------------------------------------------------------------------
// MFMA pool stage: t = mean(in[2n],in[2n+1]); out = gelu(LN(t@W+b)*g+be)
// 128 out-tokens/block, 4 waves. grid (n_out/128, 12, NB)
// in bf16 addressed in[bb*in_bs + h*h_stride + n*ts + d]; out [bb][h][n_out][64]
// ---------------------------------------------------------------------------
__global__ __launch_bounds__(256) void pool_mfma(
    const ushort_t* __restrict__ in, ushort_t* __restrict__ out,
    int n_out, long h_stride, int ts, long in_bs, long out_bs,
    const ushort_t* __restrict__ Wt, const float* __restrict__ bias,
    const float* __restrict__ g, const float* __restrict__ be)
{
  __shared__ ushort_t Wl[64 * 72];    // W^T rows padded to 72
  __shared__ ushort_t tl[128 * 72];   // pooled input, A-layout rows
  const int tid = threadIdx.x;
  const int h = blockIdx.y;
  const int bb = blockIdx.z;
  const int row0 = blockIdx.x * 128;
  in  += (size_t)bb * in_bs;
  out += (size_t)bb * out_bs;

  {
    const uint_t* ws = (const uint_t*)Wt;
    for (int i = tid; i < 2048; i += 256) {
      const int r = i >> 5, c = i & 31;
      ((uint_t*)(Wl + r * 72))[c] = ws[i];
    }
  }
  #pragma unroll
  for (int j = 0; j < 4; ++j) {
    const int idx = j * 256 + tid;
    const int rl = idx >> 3, ch = idx & 7;
    const ushort_t* p = in + (size_t)h * h_stride + (size_t)(2 * (row0 + rl)) * ts + ch * 8;
    short8 a = *(const short8*)p;
    short8 b2 = *(const short8*)(p + ts);
    short8 o;
    #pragma unroll
    for (int e = 0; e < 8; ++e)
      o[e] = (short)f2bf(0.5f * (bf2f((ushort_t)a[e]) + bf2f((ushort_t)b2[e])));
    *(short8*)&tl[rl * 72 + ch * 8] = o;
  }
  __syncthreads();

  const int w = tid >> 6, lane = tid & 63;
  const int quad = lane >> 4, l15 = lane & 15;

  float bv[4], gv[4], bev[4];
  #pragma unroll
  for (int nt = 0; nt < 4; ++nt) {
    const int c = nt * 16 + l15;
    bv[nt] = bias[c]; gv[nt] = g[c]; bev[nt] = be[c];
  }
  f32x4 a2[2][4];
  #pragma unroll
  for (int mt = 0; mt < 2; ++mt)
    #pragma unroll
    for (int nt = 0; nt < 4; ++nt)
      a2[mt][nt] = f32x4{bv[nt], bv[nt], bv[nt], bv[nt]};

  #pragma unroll
  for (int ks = 0; ks < 2; ++ks) {
    short8 af[2], bfr[4];
    #pragma unroll
    for (int mt = 0; mt < 2; ++mt)
      af[mt] = *(const short8*)&tl[(w * 32 + mt * 16 + l15) * 72 + ks * 32 + quad * 8];
    #pragma unroll
    for (int nt = 0; nt < 4; ++nt)
      bfr[nt] = *(const short8*)&Wl[(nt * 16 + l15) * 72 + ks * 32 + quad * 8];
    #pragma unroll
    for (int mt = 0; mt < 2; ++mt)
      #pragma unroll
      for (int nt = 0; nt < 4; ++nt)
        a2[mt][nt] = __builtin_amdgcn_mfma_f32_16x16x32_bf16(af[mt], bfr[nt], a2[mt][nt], 0, 0, 0);
  }

  #pragma unroll
  for (int mt = 0; mt < 2; ++mt)
    #pragma unroll
    for (int r = 0; r < 4; ++r) {
      float sum = a2[mt][0][r] + a2[mt][1][r] + a2[mt][2][r] + a2[mt][3][r];
      #pragma unroll
      for (int m = 1; m < 16; m <<= 1) sum += __shfl_xor(sum, m, 64);
      const float mu = sum * 0.015625f;
      float dv[4], var = 0.f;
      #pragma unroll
      for (int nt = 0; nt < 4; ++nt) { dv[nt] = a2[mt][nt][r] - mu; var += dv[nt] * dv[nt]; }
      #pragma unroll
      for (int m = 1; m < 16; m <<= 1) var += __shfl_xor(var, m, 64);
      const float rstd = rsqrtf(var * 0.015625f + 1e-5f);
      const int rg = row0 + w * 32 + mt * 16 + quad * 4 + r;
      #pragma unroll
      for (int nt = 0; nt < 4; ++nt) {
        const float z = dv[nt] * rstd * gv[nt] + bev[nt];
        out[((size_t)h * n_out + rg) * 64 + nt * 16 + l15] = f2bf(gelu_exact(z));
      }
    }
}

// ---------------------------------------------------------------------------
// kv partials over 32-token chunks: kc bf16, vc f32. grid (12, 16, NB)
// ---------------------------------------------------------------------------
__global__ __launch_bounds__(256) void kv_part_kernel(
    const ushort_t* __restrict__ kc, const float* __restrict__ vc,
    float* __restrict__ kvp, float* __restrict__ ksp)
{
  __shared__ float ks[32 * 64];
  __shared__ float vs[32 * 64];
  const int tid = threadIdx.x;
  const int h = blockIdx.x;
  const int c = blockIdx.y;
  const int bb = blockIdx.z;
  kc  += (size_t)bb * 393216;
  vc  += (size_t)bb * 393216;
  kvp += (size_t)bb * 786432;
  ksp += (size_t)bb * 12288;
  const ushort_t* kp = kc + ((size_t)h * 512 + c * 32) * 64;
  const float* vp = vc + ((size_t)h * 512 + c * 32) * 64;
  #pragma unroll
  for (int i = 0; i < 2; ++i) {
    ushort4 u = ((const ushort4*)kp)[tid + 256 * i];
    float4 f; f.x = bf2f(u.x); f.y = bf2f(u.y); f.z = bf2f(u.z); f.w = bf2f(u.w);
    ((float4*)ks)[tid + 256 * i] = f;
    ((float4*)vs)[tid + 256 * i] = ((const float4*)vp)[tid + 256 * i];
  }
  __syncthreads();

  const int e = tid & 63;
  const int dg = tid >> 6;
  float acc[16] = {};
  float accs = 0.f;
  for (int nn = 0; nn < 32; ++nn) {
    const float vv = vs[nn * 64 + e];
    #pragma unroll
    for (int j = 0; j < 16; ++j)
      acc[j] += ks[nn * 64 + dg * 16 + j] * vv;
    if (tid < 64) accs += ks[nn * 64 + tid];
  }
  float* o = kvp + ((size_t)h * 16 + c) * 4096;
  #pragma unroll
  for (int j = 0; j < 16; ++j)
    o[(dg * 16 + j) * 64 + e] = acc[j];
  if (tid < 64) ksp[(h * 16 + c) * 64 + tid] = accs;
}

// reduce partials -> kvxT bf16 [bb][h][80][64]: rows 0..63 = kv^T (e,d),
// row 64 = ksum, rows 65..79 = 0. grid (240, NB).
__global__ __launch_bounds__(256) void kv_reduce_t(
    const float* __restrict__ kvp, const float* __restrict__ ksp,
    ushort_t* __restrict__ kvxT)
{
  const int bb = blockIdx.y;
  kvp  += (size_t)bb * 786432;
  ksp  += (size_t)bb * 12288;
  kvxT += (size_t)bb * 61440;
  const int idx = blockIdx.x * 256 + threadIdx.x;   // < 61440
  const int h = idx / 5120;
  const int rem = idx - h * 5120;
  const int er = rem >> 6, d = rem & 63;
  const float scale = 0.044194173824159216f;  // 1/sqrt(512)
  float val = 0.f;
  if (er < 64) {
    float s = 0.f;
    #pragma unroll
    for (int c = 0; c < 16; ++c) s += kvp[((size_t)h * 16 + c) * 4096 + d * 64 + er];
    val = s * scale;
  } else if (er == 64) {
    float s = 0.f;
    #pragma unroll
    for (int c = 0; c < 16; ++c) s += ksp[(h * 16 + c) * 64 + d];
    val = s * scale;
  }
  kvxT[idx] = f2bf(val);
}

// ---------------------------------------------------------------------------
// Fused MFMA attention-apply + 3 expansion MLPs.
// grid (32, 12, NB): 128 tokens x 1 head per block. Writes bf16 (n,768).
// ---------------------------------------------------------------------------
__global__ __launch_bounds__(256) void attn_exp_mfma(
    const ushort_t* __restrict__ q16, const ushort_t* __restrict__ kvxT,
    const ushort_t* __restrict__ eWt,
    const float* __restrict__ eb, const float* __restrict__ eg,
    const float* __restrict__ ebe, ushort_t* __restrict__ out16)
{
  __shared__ ushort_t kvl[80 * 72];
  __shared__ ushort_t Wl[3 * 64 * 72];
  __shared__ ushort_t tl[128 * 72];
  const int tid = threadIdx.x;
  const int h = blockIdx.y;
  const int bb = blockIdx.z;
  const int row0 = blockIdx.x * 128;
  q16   += (size_t)bb * 3145728;
  out16 += (size_t)bb * 3145728;
  kvxT  += (size_t)bb * 61440;

  {
    const uint_t* src = (const uint_t*)(kvxT + (size_t)h * 5120);
    for (int i = tid; i < 2560; i += 256) {
      const int r = i >> 5, c = i & 31;
      ((uint_t*)(kvl + r * 72))[c] = src[i];
    }
    const uint_t* ws = (const uint_t*)eWt;
    for (int i = tid; i < 6144; i += 256) {
      const int s = i >> 11, rem = i & 2047, r = rem >> 5, c = rem & 31;
      ((uint_t*)(Wl + (s * 64 + r) * 72))[c] = ws[i];
    }
  }
  __syncthreads();

  const int w = tid >> 6, lane = tid & 63;
  const int quad = lane >> 4, l15 = lane & 15;

  // attention matmul incl. denominator column
  f32x4 acc[2][5] = {};
  #pragma unroll
  for (int ks = 0; ks < 2; ++ks) {
    short8 af[2], bfr[5];
    #pragma unroll
    for (int mt = 0; mt < 2; ++mt) {
      const int rg = row0 + w * 32 + mt * 16 + l15;
      af[mt] = *(const short8*)(q16 + (size_t)rg * 768 + h * 64 + ks * 32 + quad * 8);
    }
    #pragma unroll
    for (int nt = 0; nt < 5; ++nt)
      bfr[nt] = *(const short8*)&kvl[(nt * 16 + l15) * 72 + ks * 32 + quad * 8];
    #pragma unroll
    for (int mt = 0; mt < 2; ++mt)
      #pragma unroll
      for (int nt = 0; nt < 5; ++nt)
        acc[mt][nt] = __builtin_amdgcn_mfma_f32_16x16x32_bf16(af[mt], bfr[nt], acc[mt][nt], 0, 0, 0);
  }

  float t[2][4][4];
  #pragma unroll
  for (int mt = 0; mt < 2; ++mt)
    #pragma unroll
    for (int r = 0; r < 4; ++r) {
      const float den = __shfl(acc[mt][4][r], lane & 48, 64) + 1e-6f;
      const float inv = 1.f / den;
      #pragma unroll
      for (int nt = 0; nt < 4; ++nt)
        t[mt][nt][r] = acc[mt][nt][r] * inv;
    }

  // 3 expansion stages (s = 2, 1, 0)
  for (int s = 2; s >= 0; --s) {
    __syncthreads();
    #pragma unroll
    for (int mt = 0; mt < 2; ++mt)
      #pragma unroll
      for (int nt = 0; nt < 4; ++nt)
        #pragma unroll
        for (int r = 0; r < 4; ++r)
          tl[(w * 32 + mt * 16 + quad * 4 + r) * 72 + nt * 16 + l15] = f2bf(t[mt][nt][r]);
    __syncthreads();

    float bv[4], gv[4], bev[4];
    #pragma unroll
    for (int nt = 0; nt < 4; ++nt) {
      const int c = s * 64 + nt * 16 + l15;
      bv[nt] = eb[c]; gv[nt] = eg[c]; bev[nt] = ebe[c];
    }
    f32x4 a2[2][4];
    #pragma unroll
    for (int mt = 0; mt < 2; ++mt)
      #pragma unroll
      for (int nt = 0; nt < 4; ++nt)
        a2[mt][nt] = f32x4{bv[nt], bv[nt], bv[nt], bv[nt]};

    #pragma unroll
    for (int ks = 0; ks < 2; ++ks) {
      short8 af[2], bfr[4];
      #pragma unroll
      for (int mt = 0; mt < 2; ++mt)
        af[mt] = *(const short8*)&tl[(w * 32 + mt * 16 + l15) * 72 + ks * 32 + quad * 8];
      #pragma unroll
      for (int nt = 0; nt < 4; ++nt)
        bfr[nt] = *(const short8*)&Wl[(s * 64 + nt * 16 + l15) * 72 + ks * 32 + quad * 8];
      #pragma unroll
      for (int mt = 0; mt < 2; ++mt)
        #pragma unroll
        for (int nt = 0; nt < 4; ++nt)
          a2[mt][nt] = __builtin_amdgcn_mfma_f32_16x16x32_bf16(af[mt], bfr[nt], a2[mt][nt], 0, 0, 0);
    }

    #pragma unroll
    for (int mt = 0; mt < 2; ++mt)
      #pragma unroll
      for (int r = 0; r < 4; ++r) {
        float sum = a2[mt][0][r] + a2[mt][1][r] + a2[mt][2][r] + a2[mt][3][r];
        #pragma unroll
        for (int m = 1; m < 16; m <<= 1) sum += __shfl_xor(sum, m, 64);
        const float mu = sum * 0.015625f;
        float dv[4], var = 0.f;
        #pragma unroll
        for (int nt = 0; nt < 4; ++nt) { dv[nt] = a2[mt][nt][r] - mu; var += dv[nt] * dv[nt]; }
        #pragma unroll
        for (int m = 1; m < 16; m <<= 1) var += __shfl_xor(var, m, 64);
        const float rstd = rsqrtf(var * 0.015625f + 1e-5f);
        #pragma unroll
        for (int nt = 0; nt < 4; ++nt) {
          const float z = dv[nt] * rstd * gv[nt] + bev[nt];
          t[mt][nt][r] = gelu_exact(z);
        }
      }
  }

  #pragma unroll
  for (int mt = 0; mt < 2; ++mt)
    #pragma unroll
    for (int nt = 0; nt < 4; ++nt)
      #pragma unroll
      for (int r = 0; r < 4; ++r) {
        const int rg = row0 + w * 32 + mt * 16 + quad * 4 + r;
        out16[(size_t)rg * 768 + h * 64 + nt * 16 + l15] = f2bf(t[mt][nt][r]);
      }
}

// ---------------------------------------------------------------------------
// launch
// ---------------------------------------------------------------------------
extern "C" void kernel_launch(void* const* d_in, const int* in_sizes, int n_in,
                              void* d_out, int out_size, void* d_ws, size_t ws_size,
                              hipStream_t stream)
{
  const float* x   = (const float*)d_in[0];
  const float* Wq  = (const float*)d_in[1];
  const float* Wk  = (const float*)d_in[2];
  const float* Wv  = (const float*)d_in[3];
  const float* pW  = (const float*)d_in[4];
  const float* pb  = (const float*)d_in[5];
  const float* pg  = (const float*)d_in[6];
  const float* pbe = (const float*)d_in[7];
  const float* eW  = (const float*)d_in[8];
  const float* eb  = (const float*)d_in[9];
  const float* eg  = (const float*)d_in[10];
  const float* ebe = (const float*)d_in[11];
  const float* Wo  = (const float*)d_in[12];
  const float* bo  = (const float*)d_in[13];
  float* outp = (float*)d_out;

  // ---- workspace: fixed weight area + NB-batch chunk area ----
  unsigned char* wsb = (unsigned char*)d_ws;
  ushort_t* WqkvT = (ushort_t*)(wsb + 0);              // 3,538,944
  ushort_t* WoT   = (ushort_t*)(wsb + 3538944);        // 1,179,648
  ushort_t* Wt6   = (ushort_t*)(wsb + 4718592);        //    49,152
  const size_t CB   = 4767744;                         // chunk base
  const size_t PERB = 26075136;                        // bytes per batch

  int NB;
  if      (ws_size >= CB + 8 * PERB) NB = 8;
  else if (ws_size >= CB + 4 * PERB) NB = 4;
  else if (ws_size >= CB + 2 * PERB) NB = 2;
  else if (ws_size >= CB + 1 * PERB) NB = 1;
  else return;

  unsigned char* cb = wsb + CB;
  ushort_t* xb16 = (ushort_t*)(cb);                                  // NB*6,291,456
  ushort_t* q16  = (ushort_t*)(cb + (size_t)NB *  6291456);          // NB*6,291,456
  ushort_t* k16  = (ushort_t*)(cb + (size_t)NB * 12582912);          // NB*6,291,456
  float*    vc   = (float*)   (cb + (size_t)NB * 18874368);          // NB*1,572,864
  ushort_t* kc_a = (ushort_t*)(cb + (size_t)NB * 20447232);          // NB*3,145,728
  ushort_t* kc_b = (ushort_t*)(cb + (size_t)NB * 23592960);          // NB*1,572,864
  ushort_t* kc_c = (ushort_t*)(cb + (size_t)NB * 25165824);          // NB*  786,432
  ushort_t* kvxT = (ushort_t*)(cb + (size_t)NB * 25952256);          // NB*  122,880
  // aliases: kvp/ksp live in k16's space (k16 dead after pool stage 1);
  //          ao16 lives in xb16's space (xb16 dead after gemm_qkv).
  float* kvp = (float*)k16;
  float* ksp = (float*)((unsigned char*)k16 + (size_t)NB * 3145728);
  ushort_t* ao16 = xb16;

  const ushort_t* pWt = Wt6;
  const ushort_t* eWt = Wt6 + 3 * 4096;
  const size_t SB = (size_t)N_ * DIM_;

  transpose_w_bf16<<<dim3(24, 24), 256, 0, stream>>>(Wq, WqkvT);
  transpose_w_bf16<<<dim3(24, 24), 256, 0, stream>>>(Wk, WqkvT + 768 * 768);
  transpose_w_bf16<<<dim3(24, 24), 256, 0, stream>>>(Wv, WqkvT + 2 * 768 * 768);
  transpose_w_bf16<<<dim3(24, 24), 256, 0, stream>>>(Wo, WoT);
  transpose64_bf16<<<6, 256, 0, stream>>>(pW, eW, Wt6);

  for (int b0 = 0; b0 < B_; b0 += NB) {
    const float* xc = x + (size_t)b0 * SB;
    float* oc = outp + (size_t)b0 * SB;

    conv_f32_bf16<<<NB * 3072, 256, 0, stream>>>(xc, xb16);
    gemm_qkv<<<dim3(18, NB * 32), 256, 0, stream>>>(xb16, WqkvT, q16, k16, vc);

    // k-path pooling (MFMA), output [bb][h][n][64] bf16
    pool_mfma<<<dim3(16, 12, NB), 256, 0, stream>>>(k16, kc_a, 2048, 64L, 768,
        3145728L, 1572864L, pWt, pb, pg, pbe);
    pool_mfma<<<dim3(8, 12, NB), 256, 0, stream>>>(kc_a, kc_b, 1024, 131072L, 64,
        1572864L, 786432L, pWt + 4096, pb + 64, pg + 64, pbe + 64);
    pool_mfma<<<dim3(4, 12, NB), 256, 0, stream>>>(kc_b, kc_c, 512, 65536L, 64,
        786432L, 393216L, pWt + 8192, pb + 128, pg + 128, pbe + 128);

    kv_part_kernel<<<dim3(12, 16, NB), 256, 0, stream>>>(kc_c, vc, kvp, ksp);
    kv_reduce_t<<<dim3(240, NB), 256, 0, stream>>>(kvp, ksp, kvxT);

    attn_exp_mfma<<<dim3(32, 12, NB), 256, 0, stream>>>(q16, kvxT, eWt,
                                                        eb, eg, ebe, ao16);

    gemm_out<<<dim3(6, NB * 32), 256, 0, stream>>>(ao16, WoT, bo, oc);
  }
}

// Round 4
// 678.065 us; speedup vs baseline: 2.1615x; 1.0294x over previous
//
#include <hip/hip_runtime.h>
#include <math.h>

#define B_   8
#define N_   4096
#define DIM_ 768
#define H_   12
#define D_   64

typedef unsigned short ushort_t;
typedef unsigned int uint_t;
typedef __attribute__((ext_vector_type(8))) short short8;
typedef __attribute__((ext_vector_type(4))) float f32x4;

// ---------------------------------------------------------------------------
// helpers
// ---------------------------------------------------------------------------
__device__ __forceinline__ float gelu_exact(float z) {
  return 0.5f * z * (1.f + erff(z * 0.70710678118654752440f));
}

__device__ __forceinline__ ushort_t f2bf(float f) {
  union { float f; unsigned u; } x; x.f = f;
  unsigned r = x.u + 0x7FFFu + ((x.u >> 16) & 1u);   // RNE
  return (ushort_t)(r >> 16);
}

__device__ __forceinline__ float bf2f(ushort_t h) {
  union { unsigned u; float f; } x; x.u = ((unsigned)h) << 16;
  return x.f;
}

__device__ __forceinline__ void gl_lds16(const ushort_t* g, ushort_t* l) {
  __builtin_amdgcn_global_load_lds(
      (const __attribute__((address_space(1))) void*)g,
      (__attribute__((address_space(3))) void*)l, 16, 0, 0);
}

// ---------------------------------------------------------------------------
// 768x768 fp32 -> bf16 transposed copy (dst[n][k] = src[k][n])
// ---------------------------------------------------------------------------
__global__ __launch_bounds__(256) void transpose_w_bf16(
    const float* __restrict__ src, ushort_t* __restrict__ dst)
{
  __shared__ float t[32][33];
  const int lx = threadIdx.x & 31, ly = threadIdx.x >> 5;
  const int bx = blockIdx.x * 32;
  const int by = blockIdx.y * 32;
  #pragma unroll
  for (int j = 0; j < 32; j += 8)
    t[ly + j][lx] = src[(size_t)(by + ly + j) * 768 + bx + lx];
  __syncthreads();
  #pragma unroll
  for (int j = 0; j < 32; j += 8)
    dst[(size_t)(bx + ly + j) * 768 + by + lx] = f2bf(t[lx][ly + j]);
}

// 6x 64x64 transpose to bf16: dst[m][c][d] = src_m[d][c]; m<3 pool, else exp
__global__ __launch_bounds__(256) void transpose64_bf16(
    const float* __restrict__ pW, const float* __restrict__ eW,
    ushort_t* __restrict__ dst)
{
  const int m = blockIdx.x;
  const float* src = (m < 3) ? (pW + m * 4096) : (eW + (m - 3) * 4096);
  ushort_t* o = dst + m * 4096;
  for (int i = threadIdx.x; i < 4096; i += 256) {
    const int r = i >> 6, c = i & 63;
    o[c * 64 + r] = f2bf(src[r * 64 + c]);
  }
}

__global__ __launch_bounds__(256) void conv_f32_bf16(
    const float* __restrict__ src, ushort_t* __restrict__ dst)
{
  const int i = blockIdx.x * 256 + threadIdx.x;
  float4 f = ((const float4*)src)[i];
  ushort4 o;
  o.x = f2bf(f.x); o.y = f2bf(f.y); o.z = f2bf(f.z); o.w = f2bf(f.w);
  ((ushort4*)dst)[i] = o;
}

// ---------------------------------------------------------------------------
// x pooled by 8 tokens: x8[r][c] = mean_{j<8} xb[8r+j][c], bf16.
// one thread per 8 output cols. grid (NB*192)
// ---------------------------------------------------------------------------
__global__ __launch_bounds__(256) void pool8_x(
    const ushort_t* __restrict__ xb, ushort_t* __restrict__ x8)
{
  const int idx = blockIdx.x * 256 + threadIdx.x;   // < NB*512*96
  const int r = idx / 96, gc = idx - r * 96;
  const ushort_t* p = xb + (size_t)(8 * r) * 768 + gc * 8;
  float s[8] = {};
  #pragma unroll
  for (int j = 0; j < 8; ++j) {
    short8 v = *(const short8*)(p + (size_t)j * 768);
    #pragma unroll
    for (int e = 0; e < 8; ++e) s[e] += bf2f((ushort_t)v[e]);
  }
  short8 o;
  #pragma unroll
  for (int e = 0; e < 8; ++e) o[e] = (short)f2bf(0.125f * s[e]);
  *(short8*)(x8 + (size_t)r * 768 + gc * 8) = o;
}

// ---------------------------------------------------------------------------
// bf16 MFMA GEMM mainloop: 128x128 tile, BK=32, 4 waves 2x2, 4x4 16x16 each.
// Single-buffer (R0-proven) + bijective XCD chunk swizzle (R1-proven).
// ---------------------------------------------------------------------------
#define GEMM_MAINLOOP(A, Bt, K)                                               \
  __shared__ ushort_t As[128 * 32];                                           \
  __shared__ ushort_t Bs[128 * 32];                                           \
  const int tid = threadIdx.x;                                                \
  const int nwg_ = (int)(gridDim.x * gridDim.y);                              \
  const int wgid0_ = (int)(blockIdx.y * gridDim.x + blockIdx.x);              \
  const int wgid_ = (wgid0_ & 7) * (nwg_ >> 3) + (wgid0_ >> 3);               \
  const int row0 = (wgid_ / (int)gridDim.x) * 128;                            \
  const int col0 = (wgid_ % (int)gridDim.x) * 128;                            \
  const int sr = tid >> 2;                                                    \
  const int sk = (tid & 3) * 8;                                               \
  const ushort_t* Ag0 = (A) + (size_t)(row0 + sr) * (K) + sk;                 \
  const ushort_t* Ag1 = Ag0 + (size_t)64 * (K);                               \
  const ushort_t* Bg0 = (Bt) + (size_t)(col0 + sr) * (K) + sk;                \
  const ushort_t* Bg1 = Bg0 + (size_t)64 * (K);                               \
  ushort_t* Asw = As + (tid >> 6) * 512;                                      \
  ushort_t* Bsw = Bs + (tid >> 6) * 512;                                      \
  const int w = tid >> 6, lane = tid & 63;                                    \
  const int wm = w >> 1, wn = w & 1;                                          \
  const int qd = lane >> 4, l15 = lane & 15;                                  \
  const int aoff = (wm * 64 + l15) * 32 + qd * 8;                             \
  const int boff = (wn * 64 + l15) * 32 + qd * 8;                             \
  f32x4 acc[4][4] = {};                                                       \
  for (int k0 = 0; k0 < (K); k0 += 32) {                                      \
    __syncthreads();                                                          \
    gl_lds16(Ag0 + k0, Asw);                                                  \
    gl_lds16(Ag1 + k0, Asw + 2048);                                           \
    gl_lds16(Bg0 + k0, Bsw);                                                  \
    gl_lds16(Bg1 + k0, Bsw + 2048);                                           \
    __syncthreads();                                                          \
    short8 af[4], bfr[4];                                                     \
    _Pragma("unroll")                                                         \
    for (int mt = 0; mt < 4; ++mt) af[mt] = *(const short8*)&As[aoff + mt * 512]; \
    _Pragma("unroll")                                                         \
    for (int nt = 0; nt < 4; ++nt) bfr[nt] = *(const short8*)&Bs[boff + nt * 512]; \
    _Pragma("unroll")                                                         \
    for (int mt = 0; mt < 4; ++mt)                                            \
      _Pragma("unroll")                                                       \
      for (int nt = 0; nt < 4; ++nt)                                          \
        acc[mt][nt] = __builtin_amdgcn_mfma_f32_16x16x32_bf16(                \
            af[mt], bfr[nt], acc[mt][nt], 0, 0, 0);                           \
  }

// QKV (q,k only): q bf16 elu+1, k bf16 elu+1. grid (12, NB*32)
__global__ __launch_bounds__(256) void gemm_qkv(
    const ushort_t* __restrict__ A, const ushort_t* __restrict__ Bt,
    ushort_t* __restrict__ qo, ushort_t* __restrict__ ko)
{
  GEMM_MAINLOOP(A, Bt, 768)
  const int sel = col0 / 768;
  const int colbase = (col0 % 768) + wn * 64;
  ushort_t* o = (sel == 0) ? qo : ko;
  #pragma unroll
  for (int mt = 0; mt < 4; ++mt) {
    #pragma unroll
    for (int nt = 0; nt < 4; ++nt) {
      const int cg = colbase + nt * 16 + l15;
      #pragma unroll
      for (int r = 0; r < 4; ++r) {
        const int rg = row0 + wm * 64 + mt * 16 + qd * 4 + r;
        const float vv = acc[mt][nt][r];
        const float e = (vv > 0.f) ? vv + 1.f : __expf(vv);
        o[(size_t)rg * 768 + cg] = f2bf(e);
      }
    }
  }
}

// V GEMM on pooled x8: vc[b][h][n][64] f32 = x8 @ WvT. grid (6, NB*4)
__global__ __launch_bounds__(256) void gemm_v(
    const ushort_t* __restrict__ A, const ushort_t* __restrict__ Bt,
    float* __restrict__ vco)
{
  GEMM_MAINLOOP(A, Bt, 768)
  #pragma unroll
  for (int mt = 0; mt < 4; ++mt) {
    #pragma unroll
    for (int nt = 0; nt < 4; ++nt) {
      const int cg = col0 + wn * 64 + nt * 16 + l15;
      const int hh = cg >> 6, d = cg & 63;
      #pragma unroll
      for (int r = 0; r < 4; ++r) {
        const int rg = row0 + wm * 64 + mt * 16 + qd * 4 + r;
        const int b = rg >> 9, n = rg & 511;
        vco[(((size_t)b * 12 + hh) * 512 + n) * 64 + d] = acc[mt][nt][r];
      }
    }
  }
}

// Output GEMM + bias. grid (6, NB*32)
__global__ __launch_bounds__(256) void gemm_out(
    const ushort_t* __restrict__ A, const ushort_t* __restrict__ Bt,
    const float* __restrict__ bo, float* __restrict__ C)
{
  GEMM_MAINLOOP(A, Bt, 768)
  #pragma unroll
  for (int mt = 0; mt < 4; ++mt) {
    #pragma unroll
    for (int nt = 0; nt < 4; ++nt) {
      const int cg = col0 + wn * 64 + nt * 16 + l15;
      #pragma unroll
      for (int r = 0; r < 4; ++r) {
        const int rg = row0 + wm * 64 + mt * 16 + qd * 4 + r;
        C[(size_t)rg * 768 + cg] = acc[mt][nt][r] + bo[cg];
      }
    }
  }
}

// ---------------------------------------------------------------------------
// MFMA pool stage: t = mean(in[2n],in[2n+1]); out = gelu(LN(t@W+b)*g+be)
// 128 out-tokens/block, 4 waves. grid (n_out/128, 12, NB)
// in bf16 addressed in[bb*in_bs + h*h_stride + n*ts + d]; out [bb][h][n_out][64]
// ---------------------------------------------------------------------------
__global__ __launch_bounds__(256) void pool_mfma(
    const ushort_t* __restrict__ in, ushort_t* __restrict__ out,
    int n_out, long h_stride, int ts, long in_bs, long out_bs,
    const ushort_t* __restrict__ Wt, const float* __restrict__ bias,
    const float* __restrict__ g, const float* __restrict__ be)
{
  __shared__ ushort_t Wl[64 * 72];    // W^T rows padded to 72
  __shared__ ushort_t tl[128 * 72];   // pooled input, A-layout rows
  const int tid = threadIdx.x;
  const int h = blockIdx.y;
  const int bb = blockIdx.z;
  const int row0 = blockIdx.x * 128;
  in  += (size_t)bb * in_bs;
  out += (size_t)bb * out_bs;

  {
    const uint_t* ws = (const uint_t*)Wt;
    for (int i = tid; i < 2048; i += 256) {
      const int r = i >> 5, c = i & 31;
      ((uint_t*)(Wl + r * 72))[c] = ws[i];
    }
  }
  #pragma unroll
  for (int j = 0; j < 4; ++j) {
    const int idx = j * 256 + tid;
    const int rl = idx >> 3, ch = idx & 7;
    const ushort_t* p = in + (size_t)h * h_stride + (size_t)(2 * (row0 + rl)) * ts + ch * 8;
    short8 a = *(const short8*)p;
    short8 b2 = *(const short8*)(p + ts);
    short8 o;
    #pragma unroll
    for (int e = 0; e < 8; ++e)
      o[e] = (short)f2bf(0.5f * (bf2f((ushort_t)a[e]) + bf2f((ushort_t)b2[e])));
    *(short8*)&tl[rl * 72 + ch * 8] = o;
  }
  __syncthreads();

  const int w = tid >> 6, lane = tid & 63;
  const int quad = lane >> 4, l15 = lane & 15;

  float bv[4], gv[4], bev[4];
  #pragma unroll
  for (int nt = 0; nt < 4; ++nt) {
    const int c = nt * 16 + l15;
    bv[nt] = bias[c]; gv[nt] = g[c]; bev[nt] = be[c];
  }
  f32x4 a2[2][4];
  #pragma unroll
  for (int mt = 0; mt < 2; ++mt)
    #pragma unroll
    for (int nt = 0; nt < 4; ++nt)
      a2[mt][nt] = f32x4{bv[nt], bv[nt], bv[nt], bv[nt]};

  #pragma unroll
  for (int ks = 0; ks < 2; ++ks) {
    short8 af[2], bfr[4];
    #pragma unroll
    for (int mt = 0; mt < 2; ++mt)
      af[mt] = *(const short8*)&tl[(w * 32 + mt * 16 + l15) * 72 + ks * 32 + quad * 8];
    #pragma unroll
    for (int nt = 0; nt < 4; ++nt)
      bfr[nt] = *(const short8*)&Wl[(nt * 16 + l15) * 72 + ks * 32 + quad * 8];
    #pragma unroll
    for (int mt = 0; mt < 2; ++mt)
      #pragma unroll
      for (int nt = 0; nt < 4; ++nt)
        a2[mt][nt] = __builtin_amdgcn_mfma_f32_16x16x32_bf16(af[mt], bfr[nt], a2[mt][nt], 0, 0, 0);
  }

  #pragma unroll
  for (int mt = 0; mt < 2; ++mt)
    #pragma unroll
    for (int r = 0; r < 4; ++r) {
      float sum = a2[mt][0][r] + a2[mt][1][r] + a2[mt][2][r] + a2[mt][3][r];
      #pragma unroll
      for (int m = 1; m < 16; m <<= 1) sum += __shfl_xor(sum, m, 64);
      const float mu = sum * 0.015625f;
      float dv[4], var = 0.f;
      #pragma unroll
      for (int nt = 0; nt < 4; ++nt) { dv[nt] = a2[mt][nt][r] - mu; var += dv[nt] * dv[nt]; }
      #pragma unroll
      for (int m = 1; m < 16; m <<= 1) var += __shfl_xor(var, m, 64);
      const float rstd = rsqrtf(var * 0.015625f + 1e-5f);
      const int rg = row0 + w * 32 + mt * 16 + quad * 4 + r;
      #pragma unroll
      for (int nt = 0; nt < 4; ++nt) {
        const float z = dv[nt] * rstd * gv[nt] + bev[nt];
        out[((size_t)h * n_out + rg) * 64 + nt * 16 + l15] = f2bf(gelu_exact(z));
      }
    }
}

// ---------------------------------------------------------------------------
// kv partials over 32-token chunks: kc bf16, vc f32. grid (12, 16, NB)
// ---------------------------------------------------------------------------
__global__ __launch_bounds__(256) void kv_part_kernel(
    const ushort_t* __restrict__ kc, const float* __restrict__ vc,
    float* __restrict__ kvp, float* __restrict__ ksp)
{
  __shared__ float ks[32 * 64];
  __shared__ float vs[32 * 64];
  const int tid = threadIdx.x;
  const int h = blockIdx.x;
  const int c = blockIdx.y;
  const int bb = blockIdx.z;
  kc  += (size_t)bb * 393216;
  vc  += (size_t)bb * 393216;
  kvp += (size_t)bb * 786432;
  ksp += (size_t)bb * 12288;
  const ushort_t* kp = kc + ((size_t)h * 512 + c * 32) * 64;
  const float* vp = vc + ((size_t)h * 512 + c * 32) * 64;
  #pragma unroll
  for (int i = 0; i < 2; ++i) {
    ushort4 u = ((const ushort4*)kp)[tid + 256 * i];
    float4 f; f.x = bf2f(u.x); f.y = bf2f(u.y); f.z = bf2f(u.z); f.w = bf2f(u.w);
    ((float4*)ks)[tid + 256 * i] = f;
    ((float4*)vs)[tid + 256 * i] = ((const float4*)vp)[tid + 256 * i];
  }
  __syncthreads();

  const int e = tid & 63;
  const int dg = tid >> 6;
  float acc[16] = {};
  float accs = 0.f;
  for (int nn = 0; nn < 32; ++nn) {
    const float vv = vs[nn * 64 + e];
    #pragma unroll
    for (int j = 0; j < 16; ++j)
      acc[j] += ks[nn * 64 + dg * 16 + j] * vv;
    if (tid < 64) accs += ks[nn * 64 + tid];
  }
  float* o = kvp + ((size_t)h * 16 + c) * 4096;
  #pragma unroll
  for (int j = 0; j < 16; ++j)
    o[(dg * 16 + j) * 64 + e] = acc[j];
  if (tid < 64) ksp[(h * 16 + c) * 64 + tid] = accs;
}

// reduce partials -> kvxT bf16 [bb][h][80][64]: rows 0..63 = kv^T (e,d),
// row 64 = ksum, rows 65..79 = 0. grid (240, NB).
__global__ __launch_bounds__(256) void kv_reduce_t(
    const float* __restrict__ kvp, const float* __restrict__ ksp,
    ushort_t* __restrict__ kvxT)
{
  const int bb = blockIdx.y;
  kvp  += (size_t)bb * 786432;
  ksp  += (size_t)bb * 12288;
  kvxT += (size_t)bb * 61440;
  const int idx = blockIdx.x * 256 + threadIdx.x;   // < 61440
  const int h = idx / 5120;
  const int rem = idx - h * 5120;
  const int er = rem >> 6, d = rem & 63;
  const float scale = 0.044194173824159216f;  // 1/sqrt(512)
  float val = 0.f;
  if (er < 64) {
    float s = 0.f;
    #pragma unroll
    for (int c = 0; c < 16; ++c) s += kvp[((size_t)h * 16 + c) * 4096 + d * 64 + er];
    val = s * scale;
  } else if (er == 64) {
    float s = 0.f;
    #pragma unroll
    for (int c = 0; c < 16; ++c) s += ksp[(h * 16 + c) * 64 + d];
    val = s * scale;
  }
  kvxT[idx] = f2bf(val);
}

// ---------------------------------------------------------------------------
// Fused MFMA attention-apply + 3 expansion MLPs.
// grid (32, 12, NB): 128 tokens x 1 head per block. Writes bf16 (n,768).
// ---------------------------------------------------------------------------
__global__ __launch_bounds__(256) void attn_exp_mfma(
    const ushort_t* __restrict__ q16, const ushort_t* __restrict__ kvxT,
    const ushort_t* __restrict__ eWt,
    const float* __restrict__ eb, const float* __restrict__ eg,
    const float* __restrict__ ebe, ushort_t* __restrict__ out16)
{
  __shared__ ushort_t kvl[80 * 72];
  __shared__ ushort_t Wl[3 * 64 * 72];
  __shared__ ushort_t tl[128 * 72];
  const int tid = threadIdx.x;
  const int h = blockIdx.y;
  const int bb = blockIdx.z;
  const int row0 = blockIdx.x * 128;
  q16   += (size_t)bb * 3145728;
  out16 += (size_t)bb * 3145728;
  kvxT  += (size_t)bb * 61440;

  {
    const uint_t* src = (const uint_t*)(kvxT + (size_t)h * 5120);
    for (int i = tid; i < 2560; i += 256) {
      const int r = i >> 5, c = i & 31;
      ((uint_t*)(kvl + r * 72))[c] = src[i];
    }
    const uint_t* ws = (const uint_t*)eWt;
    for (int i = tid; i < 6144; i += 256) {
      const int s = i >> 11, rem = i & 2047, r = rem >> 5, c = rem & 31;
      ((uint_t*)(Wl + (s * 64 + r) * 72))[c] = ws[i];
    }
  }
  __syncthreads();

  const int w = tid >> 6, lane = tid & 63;
  const int quad = lane >> 4, l15 = lane & 15;

  // attention matmul incl. denominator column
  f32x4 acc[2][5] = {};
  #pragma unroll
  for (int ks = 0; ks < 2; ++ks) {
    short8 af[2], bfr[5];
    #pragma unroll
    for (int mt = 0; mt < 2; ++mt) {
      const int rg = row0 + w * 32 + mt * 16 + l15;
      af[mt] = *(const short8*)(q16 + (size_t)rg * 768 + h * 64 + ks * 32 + quad * 8);
    }
    #pragma unroll
    for (int nt = 0; nt < 5; ++nt)
      bfr[nt] = *(const short8*)&kvl[(nt * 16 + l15) * 72 + ks * 32 + quad * 8];
    #pragma unroll
    for (int mt = 0; mt < 2; ++mt)
      #pragma unroll
      for (int nt = 0; nt < 5; ++nt)
        acc[mt][nt] = __builtin_amdgcn_mfma_f32_16x16x32_bf16(af[mt], bfr[nt], acc[mt][nt], 0, 0, 0);
  }

  float t[2][4][4];
  #pragma unroll
  for (int mt = 0; mt < 2; ++mt)
    #pragma unroll
    for (int r = 0; r < 4; ++r) {
      const float den = __shfl(acc[mt][4][r], lane & 48, 64) + 1e-6f;
      const float inv = 1.f / den;
      #pragma unroll
      for (int nt = 0; nt < 4; ++nt)
        t[mt][nt][r] = acc[mt][nt][r] * inv;
    }

  // 3 expansion stages (s = 2, 1, 0)
  for (int s = 2; s >= 0; --s) {
    __syncthreads();
    #pragma unroll
    for (int mt = 0; mt < 2; ++mt)
      #pragma unroll
      for (int nt = 0; nt < 4; ++nt)
        #pragma unroll
        for (int r = 0; r < 4; ++r)
          tl[(w * 32 + mt * 16 + quad * 4 + r) * 72 + nt * 16 + l15] = f2bf(t[mt][nt][r]);
    __syncthreads();

    float bv[4], gv[4], bev[4];
    #pragma unroll
    for (int nt = 0; nt < 4; ++nt) {
      const int c = s * 64 + nt * 16 + l15;
      bv[nt] = eb[c]; gv[nt] = eg[c]; bev[nt] = ebe[c];
    }
    f32x4 a2[2][4];
    #pragma unroll
    for (int mt = 0; mt < 2; ++mt)
      #pragma unroll
      for (int nt = 0; nt < 4; ++nt)
        a2[mt][nt] = f32x4{bv[nt], bv[nt], bv[nt], bv[nt]};

    #pragma unroll
    for (int ks = 0; ks < 2; ++ks) {
      short8 af[2], bfr[4];
      #pragma unroll
      for (int mt = 0; mt < 2; ++mt)
        af[mt] = *(const short8*)&tl[(w * 32 + mt * 16 + l15) * 72 + ks * 32 + quad * 8];
      #pragma unroll
      for (int nt = 0; nt < 4; ++nt)
        bfr[nt] = *(const short8*)&Wl[(s * 64 + nt * 16 + l15) * 72 + ks * 32 + quad * 8];
      #pragma unroll
      for (int mt = 0; mt < 2; ++mt)
        #pragma unroll
        for (int nt = 0; nt < 4; ++nt)
          a2[mt][nt] = __builtin_amdgcn_mfma_f32_16x16x32_bf16(af[mt], bfr[nt], a2[mt][nt], 0, 0, 0);
    }

    #pragma unroll
    for (int mt = 0; mt < 2; ++mt)
      #pragma unroll
      for (int r = 0; r < 4; ++r) {
        float sum = a2[mt][0][r] + a2[mt][1][r] + a2[mt][2][r] + a2[mt][3][r];
        #pragma unroll
        for (int m = 1; m < 16; m <<= 1) sum += __shfl_xor(sum, m, 64);
        const float mu = sum * 0.015625f;
        float dv[4], var = 0.f;
        #pragma unroll
        for (int nt = 0; nt < 4; ++nt) { dv[nt] = a2[mt][nt][r] - mu; var += dv[nt] * dv[nt]; }
        #pragma unroll
        for (int m = 1; m < 16; m <<= 1) var += __shfl_xor(var, m, 64);
        const float rstd = rsqrtf(var * 0.015625f + 1e-5f);
        #pragma unroll
        for (int nt = 0; nt < 4; ++nt) {
          const float z = dv[nt] * rstd * gv[nt] + bev[nt];
          t[mt][nt][r] = gelu_exact(z);
        }
      }
  }

  #pragma unroll
  for (int mt = 0; mt < 2; ++mt)
    #pragma unroll
    for (int nt = 0; nt < 4; ++nt)
      #pragma unroll
      for (int r = 0; r < 4; ++r) {
        const int rg = row0 + w * 32 + mt * 16 + quad * 4 + r;
        out16[(size_t)rg * 768 + h * 64 + nt * 16 + l15] = f2bf(t[mt][nt][r]);
      }
}

// ---------------------------------------------------------------------------
// launch
// ---------------------------------------------------------------------------
extern "C" void kernel_launch(void* const* d_in, const int* in_sizes, int n_in,
                              void* d_out, int out_size, void* d_ws, size_t ws_size,
                              hipStream_t stream)
{
  const float* x   = (const float*)d_in[0];
  const float* Wq  = (const float*)d_in[1];
  const float* Wk  = (const float*)d_in[2];
  const float* Wv  = (const float*)d_in[3];
  const float* pW  = (const float*)d_in[4];
  const float* pb  = (const float*)d_in[5];
  const float* pg  = (const float*)d_in[6];
  const float* pbe = (const float*)d_in[7];
  const float* eW  = (const float*)d_in[8];
  const float* eb  = (const float*)d_in[9];
  const float* eg  = (const float*)d_in[10];
  const float* ebe = (const float*)d_in[11];
  const float* Wo  = (const float*)d_in[12];
  const float* bo  = (const float*)d_in[13];
  float* outp = (float*)d_out;

  // ---- workspace: fixed weight area + NB-batch chunk area ----
  unsigned char* wsb = (unsigned char*)d_ws;
  ushort_t* WqkvT = (ushort_t*)(wsb + 0);              // 3,538,944
  ushort_t* WoT   = (ushort_t*)(wsb + 3538944);        // 1,179,648
  ushort_t* Wt6   = (ushort_t*)(wsb + 4718592);        //    49,152
  const size_t CB   = 4767744;                         // chunk base
  const size_t PERB = 26861568;                        // bytes per batch

  int NB;
  if      (ws_size >= CB + 8 * PERB) NB = 8;
  else if (ws_size >= CB + 4 * PERB) NB = 4;
  else if (ws_size >= CB + 2 * PERB) NB = 2;
  else if (ws_size >= CB + 1 * PERB) NB = 1;
  else return;

  unsigned char* cb = wsb + CB;
  ushort_t* xb16 = (ushort_t*)(cb);                                  // NB*6,291,456
  ushort_t* q16  = (ushort_t*)(cb + (size_t)NB *  6291456);          // NB*6,291,456
  ushort_t* k16  = (ushort_t*)(cb + (size_t)NB * 12582912);          // NB*6,291,456
  float*    vc   = (float*)   (cb + (size_t)NB * 18874368);          // NB*1,572,864
  ushort_t* kc_a = (ushort_t*)(cb + (size_t)NB * 20447232);          // NB*3,145,728
  ushort_t* kc_b = (ushort_t*)(cb + (size_t)NB * 23592960);          // NB*1,572,864
  ushort_t* kc_c = (ushort_t*)(cb + (size_t)NB * 25165824);          // NB*  786,432
  ushort_t* kvxT = (ushort_t*)(cb + (size_t)NB * 25952256);          // NB*  122,880
  ushort_t* x8   = (ushort_t*)(cb + (size_t)NB * 26075136);          // NB*  786,432
  // aliases: kvp/ksp live in k16's space (k16 dead after pool stage 1);
  //          ao16 lives in xb16's space (xb16 dead after gemm_qkv/gemm_v).
  float* kvp = (float*)k16;
  float* ksp = (float*)((unsigned char*)k16 + (size_t)NB * 3145728);
  ushort_t* ao16 = xb16;

  const ushort_t* pWt = Wt6;
  const ushort_t* eWt = Wt6 + 3 * 4096;
  const size_t SB = (size_t)N_ * DIM_;

  transpose_w_bf16<<<dim3(24, 24), 256, 0, stream>>>(Wq, WqkvT);
  transpose_w_bf16<<<dim3(24, 24), 256, 0, stream>>>(Wk, WqkvT + 768 * 768);
  transpose_w_bf16<<<dim3(24, 24), 256, 0, stream>>>(Wv, WqkvT + 2 * 768 * 768);
  transpose_w_bf16<<<dim3(24, 24), 256, 0, stream>>>(Wo, WoT);
  transpose64_bf16<<<6, 256, 0, stream>>>(pW, eW, Wt6);

  const ushort_t* WvT = WqkvT + 2 * 768 * 768;

  for (int b0 = 0; b0 < B_; b0 += NB) {
    const float* xc = x + (size_t)b0 * SB;
    float* oc = outp + (size_t)b0 * SB;

    conv_f32_bf16<<<NB * 3072, 256, 0, stream>>>(xc, xb16);
    pool8_x<<<NB * 192, 256, 0, stream>>>(xb16, x8);
    gemm_qkv<<<dim3(12, NB * 32), 256, 0, stream>>>(xb16, WqkvT, q16, k16);
    gemm_v<<<dim3(6, NB * 4), 256, 0, stream>>>(x8, WvT, vc);

    // k-path pooling (MFMA), output [bb][h][n][64] bf16
    pool_mfma<<<dim3(16, 12, NB), 256, 0, stream>>>(k16, kc_a, 2048, 64L, 768,
        3145728L, 1572864L, pWt, pb, pg, pbe);
    pool_mfma<<<dim3(8, 12, NB), 256, 0, stream>>>(kc_a, kc_b, 1024, 131072L, 64,
        1572864L, 786432L, pWt + 4096, pb + 64, pg + 64, pbe + 64);
    pool_mfma<<<dim3(4, 12, NB), 256, 0, stream>>>(kc_b, kc_c, 512, 65536L, 64,
        786432L, 393216L, pWt + 8192, pb + 128, pg + 128, pbe + 128);

    kv_part_kernel<<<dim3(12, 16, NB), 256, 0, stream>>>(kc_c, vc, kvp, ksp);
    kv_reduce_t<<<dim3(240, NB), 256, 0, stream>>>(kvp, ksp, kvxT);

    attn_exp_mfma<<<dim3(32, 12, NB), 256, 0, stream>>>(q16, kvxT, eWt,
                                                        eb, eg, ebe, ao16);

    gemm_out<<<dim3(6, NB * 32), 256, 0, stream>>>(ao16, WoT, bo, oc);
  }
}

// Round 5
// 586.496 us; speedup vs baseline: 2.4990x; 1.1561x over previous
//
#include <hip/hip_runtime.h>
#include <math.h>

#define B_   8
#define N_   4096
#define DIM_ 768
#define H_   12
#define D_   64

typedef unsigned short ushort_t;
typedef unsigned int uint_t;
typedef __attribute__((ext_vector_type(8))) short short8;
typedef __attribute__((ext_vector_type(4))) float f32x4;

// ---------------------------------------------------------------------------
// helpers
// ---------------------------------------------------------------------------
// gelu with Abramowitz-Stegun 7.1.26 erf (|err| <= 1.5e-7, branch-free):
// ~12 VALU + v_exp_f32 + v_rcp_f32 vs libm erff's long divergent expansion.
__device__ __forceinline__ float gelu_exact(float z) {
  const float ax = fabsf(z) * 0.70710678118654752440f;
  const float t  = __builtin_amdgcn_rcpf(1.f + 0.3275911f * ax);
  float poly = ((((1.061405429f * t - 1.453152027f) * t + 1.421413741f) * t
                 - 0.284496736f) * t + 0.254829592f) * t;
  const float erfax = 1.f - poly * __expf(-ax * ax);
  const float erfv = __builtin_copysignf(erfax, z);
  return 0.5f * z * (1.f + erfv);
}

__device__ __forceinline__ ushort_t f2bf(float f) {
  union { float f; unsigned u; } x; x.f = f;
  unsigned r = x.u + 0x7FFFu + ((x.u >> 16) & 1u);   // RNE
  return (ushort_t)(r >> 16);
}

__device__ __forceinline__ float bf2f(ushort_t h) {
  union { unsigned u; float f; } x; x.u = ((unsigned)h) << 16;
  return x.f;
}

__device__ __forceinline__ void gl_lds16(const ushort_t* g, ushort_t* l) {
  __builtin_amdgcn_global_load_lds(
      (const __attribute__((address_space(1))) void*)g,
      (__attribute__((address_space(3))) void*)l, 16, 0, 0);
}

// ---------------------------------------------------------------------------
// 768x768 fp32 -> bf16 transposed copy (dst[n][k] = src[k][n])
// ---------------------------------------------------------------------------
__global__ __launch_bounds__(256) void transpose_w_bf16(
    const float* __restrict__ src, ushort_t* __restrict__ dst)
{
  __shared__ float t[32][33];
  const int lx = threadIdx.x & 31, ly = threadIdx.x >> 5;
  const int bx = blockIdx.x * 32;
  const int by = blockIdx.y * 32;
  #pragma unroll
  for (int j = 0; j < 32; j += 8)
    t[ly + j][lx] = src[(size_t)(by + ly + j) * 768 + bx + lx];
  __syncthreads();
  #pragma unroll
  for (int j = 0; j < 32; j += 8)
    dst[(size_t)(bx + ly + j) * 768 + by + lx] = f2bf(t[lx][ly + j]);
}

// 6x 64x64 transpose to bf16: dst[m][c][d] = src_m[d][c]; m<3 pool, else exp
__global__ __launch_bounds__(256) void transpose64_bf16(
    const float* __restrict__ pW, const float* __restrict__ eW,
    ushort_t* __restrict__ dst)
{
  const int m = blockIdx.x;
  const float* src = (m < 3) ? (pW + m * 4096) : (eW + (m - 3) * 4096);
  ushort_t* o = dst + m * 4096;
  for (int i = threadIdx.x; i < 4096; i += 256) {
    const int r = i >> 6, c = i & 63;
    o[c * 64 + r] = f2bf(src[r * 64 + c]);
  }
}

__global__ __launch_bounds__(256) void conv_f32_bf16(
    const float* __restrict__ src, ushort_t* __restrict__ dst)
{
  const int i = blockIdx.x * 256 + threadIdx.x;
  float4 f = ((const float4*)src)[i];
  ushort4 o;
  o.x = f2bf(f.x); o.y = f2bf(f.y); o.z = f2bf(f.z); o.w = f2bf(f.w);
  ((ushort4*)dst)[i] = o;
}

// ---------------------------------------------------------------------------
// x pooled by 8 tokens: x8[r][c] = mean_{j<8} xb[8r+j][c], bf16.
// one thread per 8 output cols. grid (NB*192)
// ---------------------------------------------------------------------------
__global__ __launch_bounds__(256) void pool8_x(
    const ushort_t* __restrict__ xb, ushort_t* __restrict__ x8)
{
  const int idx = blockIdx.x * 256 + threadIdx.x;   // < NB*512*96
  const int r = idx / 96, gc = idx - r * 96;
  const ushort_t* p = xb + (size_t)(8 * r) * 768 + gc * 8;
  float s[8] = {};
  #pragma unroll
  for (int j = 0; j < 8; ++j) {
    short8 v = *(const short8*)(p + (size_t)j * 768);
    #pragma unroll
    for (int e = 0; e < 8; ++e) s[e] += bf2f((ushort_t)v[e]);
  }
  short8 o;
  #pragma unroll
  for (int e = 0; e < 8; ++e) o[e] = (short)f2bf(0.125f * s[e]);
  *(short8*)(x8 + (size_t)r * 768 + gc * 8) = o;
}

// ---------------------------------------------------------------------------
// bf16 MFMA GEMM mainloop: 128x128 tile, BK=32, 4 waves 2x2, 4x4 16x16 each.
// Single-buffer (R0-proven) + bijective XCD chunk swizzle (R1-proven).
// ---------------------------------------------------------------------------
#define GEMM_MAINLOOP(A, Bt, K)                                               \
  __shared__ ushort_t As[128 * 32];                                           \
  __shared__ ushort_t Bs[128 * 32];                                           \
  const int tid = threadIdx.x;                                                \
  const int nwg_ = (int)(gridDim.x * gridDim.y);                              \
  const int wgid0_ = (int)(blockIdx.y * gridDim.x + blockIdx.x);              \
  const int wgid_ = (wgid0_ & 7) * (nwg_ >> 3) + (wgid0_ >> 3);               \
  const int row0 = (wgid_ / (int)gridDim.x) * 128;                            \
  const int col0 = (wgid_ % (int)gridDim.x) * 128;                            \
  const int sr = tid >> 2;                                                    \
  const int sk = (tid & 3) * 8;                                               \
  const ushort_t* Ag0 = (A) + (size_t)(row0 + sr) * (K) + sk;                 \
  const ushort_t* Ag1 = Ag0 + (size_t)64 * (K);                               \
  const ushort_t* Bg0 = (Bt) + (size_t)(col0 + sr) * (K) + sk;                \
  const ushort_t* Bg1 = Bg0 + (size_t)64 * (K);                               \
  ushort_t* Asw = As + (tid >> 6) * 512;                                      \
  ushort_t* Bsw = Bs + (tid >> 6) * 512;                                      \
  const int w = tid >> 6, lane = tid & 63;                                    \
  const int wm = w >> 1, wn = w & 1;                                          \
  const int qd = lane >> 4, l15 = lane & 15;                                  \
  const int aoff = (wm * 64 + l15) * 32 + qd * 8;                             \
  const int boff = (wn * 64 + l15) * 32 + qd * 8;                             \
  f32x4 acc[4][4] = {};                                                       \
  for (int k0 = 0; k0 < (K); k0 += 32) {                                      \
    __syncthreads();                                                          \
    gl_lds16(Ag0 + k0, Asw);                                                  \
    gl_lds16(Ag1 + k0, Asw + 2048);                                           \
    gl_lds16(Bg0 + k0, Bsw);                                                  \
    gl_lds16(Bg1 + k0, Bsw + 2048);                                           \
    __syncthreads();                                                          \
    short8 af[4], bfr[4];                                                     \
    _Pragma("unroll")                                                         \
    for (int mt = 0; mt < 4; ++mt) af[mt] = *(const short8*)&As[aoff + mt * 512]; \
    _Pragma("unroll")                                                         \
    for (int nt = 0; nt < 4; ++nt) bfr[nt] = *(const short8*)&Bs[boff + nt * 512]; \
    _Pragma("unroll")                                                         \
    for (int mt = 0; mt < 4; ++mt)                                            \
      _Pragma("unroll")                                                       \
      for (int nt = 0; nt < 4; ++nt)                                          \
        acc[mt][nt] = __builtin_amdgcn_mfma_f32_16x16x32_bf16(                \
            af[mt], bfr[nt], acc[mt][nt], 0, 0, 0);                           \
  }

// QKV (q,k only): q bf16 elu+1, k bf16 elu+1. grid (12, NB*32)
__global__ __launch_bounds__(256) void gemm_qkv(
    const ushort_t* __restrict__ A, const ushort_t* __restrict__ Bt,
    ushort_t* __restrict__ qo, ushort_t* __restrict__ ko)
{
  GEMM_MAINLOOP(A, Bt, 768)
  const int sel = col0 / 768;
  const int colbase = (col0 % 768) + wn * 64;
  ushort_t* o = (sel == 0) ? qo : ko;
  #pragma unroll
  for (int mt = 0; mt < 4; ++mt) {
    #pragma unroll
    for (int nt = 0; nt < 4; ++nt) {
      const int cg = colbase + nt * 16 + l15;
      #pragma unroll
      for (int r = 0; r < 4; ++r) {
        const int rg = row0 + wm * 64 + mt * 16 + qd * 4 + r;
        const float vv = acc[mt][nt][r];
        const float e = (vv > 0.f) ? vv + 1.f : __expf(vv);
        o[(size_t)rg * 768 + cg] = f2bf(e);
      }
    }
  }
}

// V GEMM on pooled x8: vc[b][h][n][64] f32 = x8 @ WvT. grid (6, NB*4)
__global__ __launch_bounds__(256) void gemm_v(
    const ushort_t* __restrict__ A, const ushort_t* __restrict__ Bt,
    float* __restrict__ vco)
{
  GEMM_MAINLOOP(A, Bt, 768)
  #pragma unroll
  for (int mt = 0; mt < 4; ++mt) {
    #pragma unroll
    for (int nt = 0; nt < 4; ++nt) {
      const int cg = col0 + wn * 64 + nt * 16 + l15;
      const int hh = cg >> 6, d = cg & 63;
      #pragma unroll
      for (int r = 0; r < 4; ++r) {
        const int rg = row0 + wm * 64 + mt * 16 + qd * 4 + r;
        const int b = rg >> 9, n = rg & 511;
        vco[(((size_t)b * 12 + hh) * 512 + n) * 64 + d] = acc[mt][nt][r];
      }
    }
  }
}

// Output GEMM + bias. grid (6, NB*32)
__global__ __launch_bounds__(256) void gemm_out(
    const ushort_t* __restrict__ A, const ushort_t* __restrict__ Bt,
    const float* __restrict__ bo, float* __restrict__ C)
{
  GEMM_MAINLOOP(A, Bt, 768)
  #pragma unroll
  for (int mt = 0; mt < 4; ++mt) {
    #pragma unroll
    for (int nt = 0; nt < 4; ++nt) {
      const int cg = col0 + wn * 64 + nt * 16 + l15;
      #pragma unroll
      for (int r = 0; r < 4; ++r) {
        const int rg = row0 + wm * 64 + mt * 16 + qd * 4 + r;
        C[(size_t)rg * 768 + cg] = acc[mt][nt][r] + bo[cg];
      }
    }
  }
}

// ---------------------------------------------------------------------------
// MFMA pool stage: t = mean(in[2n],in[2n+1]); out = gelu(LN(t@W+b)*g+be)
// 128 out-tokens/block, 4 waves. grid (n_out/128, 12, NB)
// in bf16 addressed in[bb*in_bs + h*h_stride + n*ts + d]; out [bb][h][n_out][64]
// ---------------------------------------------------------------------------
__global__ __launch_bounds__(256) void pool_mfma(
    const ushort_t* __restrict__ in, ushort_t* __restrict__ out,
    int n_out, long h_stride, int ts, long in_bs, long out_bs,
    const ushort_t* __restrict__ Wt, const float* __restrict__ bias,
    const float* __restrict__ g, const float* __restrict__ be)
{
  __shared__ ushort_t Wl[64 * 72];    // W^T rows padded to 72
  __shared__ ushort_t tl[128 * 72];   // pooled input, A-layout rows
  const int tid = threadIdx.x;
  const int h = blockIdx.y;
  const int bb = blockIdx.z;
  const int row0 = blockIdx.x * 128;
  in  += (size_t)bb * in_bs;
  out += (size_t)bb * out_bs;

  {
    const uint_t* ws = (const uint_t*)Wt;
    for (int i = tid; i < 2048; i += 256) {
      const int r = i >> 5, c = i & 31;
      ((uint_t*)(Wl + r * 72))[c] = ws[i];
    }
  }
  #pragma unroll
  for (int j = 0; j < 4; ++j) {
    const int idx = j * 256 + tid;
    const int rl = idx >> 3, ch = idx & 7;
    const ushort_t* p = in + (size_t)h * h_stride + (size_t)(2 * (row0 + rl)) * ts + ch * 8;
    short8 a = *(const short8*)p;
    short8 b2 = *(const short8*)(p + ts);
    short8 o;
    #pragma unroll
    for (int e = 0; e < 8; ++e)
      o[e] = (short)f2bf(0.5f * (bf2f((ushort_t)a[e]) + bf2f((ushort_t)b2[e])));
    *(short8*)&tl[rl * 72 + ch * 8] = o;
  }
  __syncthreads();

  const int w = tid >> 6, lane = tid & 63;
  const int quad = lane >> 4, l15 = lane & 15;

  float bv[4], gv[4], bev[4];
  #pragma unroll
  for (int nt = 0; nt < 4; ++nt) {
    const int c = nt * 16 + l15;
    bv[nt] = bias[c]; gv[nt] = g[c]; bev[nt] = be[c];
  }
  f32x4 a2[2][4];
  #pragma unroll
  for (int mt = 0; mt < 2; ++mt)
    #pragma unroll
    for (int nt = 0; nt < 4; ++nt)
      a2[mt][nt] = f32x4{bv[nt], bv[nt], bv[nt], bv[nt]};

  #pragma unroll
  for (int ks = 0; ks < 2; ++ks) {
    short8 af[2], bfr[4];
    #pragma unroll
    for (int mt = 0; mt < 2; ++mt)
      af[mt] = *(const short8*)&tl[(w * 32 + mt * 16 + l15) * 72 + ks * 32 + quad * 8];
    #pragma unroll
    for (int nt = 0; nt < 4; ++nt)
      bfr[nt] = *(const short8*)&Wl[(nt * 16 + l15) * 72 + ks * 32 + quad * 8];
    #pragma unroll
    for (int mt = 0; mt < 2; ++mt)
      #pragma unroll
      for (int nt = 0; nt < 4; ++nt)
        a2[mt][nt] = __builtin_amdgcn_mfma_f32_16x16x32_bf16(af[mt], bfr[nt], a2[mt][nt], 0, 0, 0);
  }

  #pragma unroll
  for (int mt = 0; mt < 2; ++mt)
    #pragma unroll
    for (int r = 0; r < 4; ++r) {
      float sum = a2[mt][0][r] + a2[mt][1][r] + a2[mt][2][r] + a2[mt][3][r];
      #pragma unroll
      for (int m = 1; m < 16; m <<= 1) sum += __shfl_xor(sum, m, 64);
      const float mu = sum * 0.015625f;
      float dv[4], var = 0.f;
      #pragma unroll
      for (int nt = 0; nt < 4; ++nt) { dv[nt] = a2[mt][nt][r] - mu; var += dv[nt] * dv[nt]; }
      #pragma unroll
      for (int m = 1; m < 16; m <<= 1) var += __shfl_xor(var, m, 64);
      const float rstd = rsqrtf(var * 0.015625f + 1e-5f);
      const int rg = row0 + w * 32 + mt * 16 + quad * 4 + r;
      #pragma unroll
      for (int nt = 0; nt < 4; ++nt) {
        const float z = dv[nt] * rstd * gv[nt] + bev[nt];
        out[((size_t)h * n_out + rg) * 64 + nt * 16 + l15] = f2bf(gelu_exact(z));
      }
    }
}

// ---------------------------------------------------------------------------
// kv partials over 32-token chunks: kc bf16, vc f32. grid (12, 16, NB)
// ---------------------------------------------------------------------------
__global__ __launch_bounds__(256) void kv_part_kernel(
    const ushort_t* __restrict__ kc, const float* __restrict__ vc,
    float* __restrict__ kvp, float* __restrict__ ksp)
{
  __shared__ float ks[32 * 64];
  __shared__ float vs[32 * 64];
  const int tid = threadIdx.x;
  const int h = blockIdx.x;
  const int c = blockIdx.y;
  const int bb = blockIdx.z;
  kc  += (size_t)bb * 393216;
  vc  += (size_t)bb * 393216;
  kvp += (size_t)bb * 786432;
  ksp += (size_t)bb * 12288;
  const ushort_t* kp = kc + ((size_t)h * 512 + c * 32) * 64;
  const float* vp = vc + ((size_t)h * 512 + c * 32) * 64;
  #pragma unroll
  for (int i = 0; i < 2; ++i) {
    ushort4 u = ((const ushort4*)kp)[tid + 256 * i];
    float4 f; f.x = bf2f(u.x); f.y = bf2f(u.y); f.z = bf2f(u.z); f.w = bf2f(u.w);
    ((float4*)ks)[tid + 256 * i] = f;
    ((float4*)vs)[tid + 256 * i] = ((const float4*)vp)[tid + 256 * i];
  }
  __syncthreads();

  const int e = tid & 63;
  const int dg = tid >> 6;
  float acc[16] = {};
  float accs = 0.f;
  for (int nn = 0; nn < 32; ++nn) {
    const float vv = vs[nn * 64 + e];
    #pragma unroll
    for (int j = 0; j < 16; ++j)
      acc[j] += ks[nn * 64 + dg * 16 + j] * vv;
    if (tid < 64) accs += ks[nn * 64 + tid];
  }
  float* o = kvp + ((size_t)h * 16 + c) * 4096;
  #pragma unroll
  for (int j = 0; j < 16; ++j)
    o[(dg * 16 + j) * 64 + e] = acc[j];
  if (tid < 64) ksp[(h * 16 + c) * 64 + tid] = accs;
}

// reduce partials -> kvxT bf16 [bb][h][80][64]: rows 0..63 = kv^T (e,d),
// row 64 = ksum, rows 65..79 = 0. grid (240, NB).
__global__ __launch_bounds__(256) void kv_reduce_t(
    const float* __restrict__ kvp, const float* __restrict__ ksp,
    ushort_t* __restrict__ kvxT)
{
  const int bb = blockIdx.y;
  kvp  += (size_t)bb * 786432;
  ksp  += (size_t)bb * 12288;
  kvxT += (size_t)bb * 61440;
  const int idx = blockIdx.x * 256 + threadIdx.x;   // < 61440
  const int h = idx / 5120;
  const int rem = idx - h * 5120;
  const int er = rem >> 6, d = rem & 63;
  const float scale = 0.044194173824159216f;  // 1/sqrt(512)
  float val = 0.f;
  if (er < 64) {
    float s = 0.f;
    #pragma unroll
    for (int c = 0; c < 16; ++c) s += kvp[((size_t)h * 16 + c) * 4096 + d * 64 + er];
    val = s * scale;
  } else if (er == 64) {
    float s = 0.f;
    #pragma unroll
    for (int c = 0; c < 16; ++c) s += ksp[(h * 16 + c) * 64 + d];
    val = s * scale;
  }
  kvxT[idx] = f2bf(val);
}

// ---------------------------------------------------------------------------
// Fused MFMA attention-apply + 3 expansion MLPs.
// grid (32, 12, NB): 128 tokens x 1 head per block. Writes bf16 (n,768).
// kv fragments read straight from global (kvxT is L2-resident) -> less LDS.
// ---------------------------------------------------------------------------
__global__ __launch_bounds__(256) void attn_exp_mfma(
    const ushort_t* __restrict__ q16, const ushort_t* __restrict__ kvxT,
    const ushort_t* __restrict__ eWt,
    const float* __restrict__ eb, const float* __restrict__ eg,
    const float* __restrict__ ebe, ushort_t* __restrict__ out16)
{
  __shared__ ushort_t Wl[3 * 64 * 72];
  __shared__ ushort_t tl[128 * 72];
  const int tid = threadIdx.x;
  const int h = blockIdx.y;
  const int bb = blockIdx.z;
  const int row0 = blockIdx.x * 128;
  q16   += (size_t)bb * 3145728;
  out16 += (size_t)bb * 3145728;
  const ushort_t* kvx = kvxT + (size_t)bb * 61440 + (size_t)h * 5120;

  {
    const uint_t* ws = (const uint_t*)eWt;
    for (int i = tid; i < 6144; i += 256) {
      const int s = i >> 11, rem = i & 2047, r = rem >> 5, c = rem & 31;
      ((uint_t*)(Wl + (s * 64 + r) * 72))[c] = ws[i];
    }
  }
  __syncthreads();

  const int w = tid >> 6, lane = tid & 63;
  const int quad = lane >> 4, l15 = lane & 15;

  // attention matmul incl. denominator column
  f32x4 acc[2][5] = {};
  #pragma unroll
  for (int ks = 0; ks < 2; ++ks) {
    short8 af[2], bfr[5];
    #pragma unroll
    for (int mt = 0; mt < 2; ++mt) {
      const int rg = row0 + w * 32 + mt * 16 + l15;
      af[mt] = *(const short8*)(q16 + (size_t)rg * 768 + h * 64 + ks * 32 + quad * 8);
    }
    #pragma unroll
    for (int nt = 0; nt < 5; ++nt)
      bfr[nt] = *(const short8*)(kvx + (nt * 16 + l15) * 64 + ks * 32 + quad * 8);
    #pragma unroll
    for (int mt = 0; mt < 2; ++mt)
      #pragma unroll
      for (int nt = 0; nt < 5; ++nt)
        acc[mt][nt] = __builtin_amdgcn_mfma_f32_16x16x32_bf16(af[mt], bfr[nt], acc[mt][nt], 0, 0, 0);
  }

  float t[2][4][4];
  #pragma unroll
  for (int mt = 0; mt < 2; ++mt)
    #pragma unroll
    for (int r = 0; r < 4; ++r) {
      const float den = __shfl(acc[mt][4][r], lane & 48, 64) + 1e-6f;
      const float inv = __builtin_amdgcn_rcpf(den);
      #pragma unroll
      for (int nt = 0; nt < 4; ++nt)
        t[mt][nt][r] = acc[mt][nt][r] * inv;
    }

  // 3 expansion stages (s = 2, 1, 0)
  for (int s = 2; s >= 0; --s) {
    __syncthreads();
    #pragma unroll
    for (int mt = 0; mt < 2; ++mt)
      #pragma unroll
      for (int nt = 0; nt < 4; ++nt)
        #pragma unroll
        for (int r = 0; r < 4; ++r)
          tl[(w * 32 + mt * 16 + quad * 4 + r) * 72 + nt * 16 + l15] = f2bf(t[mt][nt][r]);
    __syncthreads();

    float bv[4], gv[4], bev[4];
    #pragma unroll
    for (int nt = 0; nt < 4; ++nt) {
      const int c = s * 64 + nt * 16 + l15;
      bv[nt] = eb[c]; gv[nt] = eg[c]; bev[nt] = ebe[c];
    }
    f32x4 a2[2][4];
    #pragma unroll
    for (int mt = 0; mt < 2; ++mt)
      #pragma unroll
      for (int nt = 0; nt < 4; ++nt)
        a2[mt][nt] = f32x4{bv[nt], bv[nt], bv[nt], bv[nt]};

    #pragma unroll
    for (int ks = 0; ks < 2; ++ks) {
      short8 af[2], bfr[4];
      #pragma unroll
      for (int mt = 0; mt < 2; ++mt)
        af[mt] = *(const short8*)&tl[(w * 32 + mt * 16 + l15) * 72 + ks * 32 + quad * 8];
      #pragma unroll
      for (int nt = 0; nt < 4; ++nt)
        bfr[nt] = *(const short8*)&Wl[(s * 64 + nt * 16 + l15) * 72 + ks * 32 + quad * 8];
      #pragma unroll
      for (int mt = 0; mt < 2; ++mt)
        #pragma unroll
        for (int nt = 0; nt < 4; ++nt)
          a2[mt][nt] = __builtin_amdgcn_mfma_f32_16x16x32_bf16(af[mt], bfr[nt], a2[mt][nt], 0, 0, 0);
    }

    #pragma unroll
    for (int mt = 0; mt < 2; ++mt)
      #pragma unroll
      for (int r = 0; r < 4; ++r) {
        float sum = a2[mt][0][r] + a2[mt][1][r] + a2[mt][2][r] + a2[mt][3][r];
        #pragma unroll
        for (int m = 1; m < 16; m <<= 1) sum += __shfl_xor(sum, m, 64);
        const float mu = sum * 0.015625f;
        float dv[4], var = 0.f;
        #pragma unroll
        for (int nt = 0; nt < 4; ++nt) { dv[nt] = a2[mt][nt][r] - mu; var += dv[nt] * dv[nt]; }
        #pragma unroll
        for (int m = 1; m < 16; m <<= 1) var += __shfl_xor(var, m, 64);
        const float rstd = rsqrtf(var * 0.015625f + 1e-5f);
        #pragma unroll
        for (int nt = 0; nt < 4; ++nt) {
          const float z = dv[nt] * rstd * gv[nt] + bev[nt];
          t[mt][nt][r] = gelu_exact(z);
        }
      }
  }

  #pragma unroll
  for (int mt = 0; mt < 2; ++mt)
    #pragma unroll
    for (int nt = 0; nt < 4; ++nt)
      #pragma unroll
      for (int r = 0; r < 4; ++r) {
        const int rg = row0 + w * 32 + mt * 16 + quad * 4 + r;
        out16[(size_t)rg * 768 + h * 64 + nt * 16 + l15] = f2bf(t[mt][nt][r]);
      }
}

// ---------------------------------------------------------------------------
// launch
// ---------------------------------------------------------------------------
extern "C" void kernel_launch(void* const* d_in, const int* in_sizes, int n_in,
                              void* d_out, int out_size, void* d_ws, size_t ws_size,
                              hipStream_t stream)
{
  const float* x   = (const float*)d_in[0];
  const float* Wq  = (const float*)d_in[1];
  const float* Wk  = (const float*)d_in[2];
  const float* Wv  = (const float*)d_in[3];
  const float* pW  = (const float*)d_in[4];
  const float* pb  = (const float*)d_in[5];
  const float* pg  = (const float*)d_in[6];
  const float* pbe = (const float*)d_in[7];
  const float* eW  = (const float*)d_in[8];
  const float* eb  = (const float*)d_in[9];
  const float* eg  = (const float*)d_in[10];
  const float* ebe = (const float*)d_in[11];
  const float* Wo  = (const float*)d_in[12];
  const float* bo  = (const float*)d_in[13];
  float* outp = (float*)d_out;

  // ---- workspace: fixed weight area + NB-batch chunk area ----
  unsigned char* wsb = (unsigned char*)d_ws;
  ushort_t* WqkvT = (ushort_t*)(wsb + 0);              // 3,538,944
  ushort_t* WoT   = (ushort_t*)(wsb + 3538944);        // 1,179,648
  ushort_t* Wt6   = (ushort_t*)(wsb + 4718592);        //    49,152
  const size_t CB   = 4767744;                         // chunk base
  const size_t PERB = 26861568;                        // bytes per batch

  int NB;
  if      (ws_size >= CB + 8 * PERB) NB = 8;
  else if (ws_size >= CB + 4 * PERB) NB = 4;
  else if (ws_size >= CB + 2 * PERB) NB = 2;
  else if (ws_size >= CB + 1 * PERB) NB = 1;
  else return;

  unsigned char* cb = wsb + CB;
  ushort_t* xb16 = (ushort_t*)(cb);                                  // NB*6,291,456
  ushort_t* q16  = (ushort_t*)(cb + (size_t)NB *  6291456);          // NB*6,291,456
  ushort_t* k16  = (ushort_t*)(cb + (size_t)NB * 12582912);          // NB*6,291,456
  float*    vc   = (float*)   (cb + (size_t)NB * 18874368);          // NB*1,572,864
  ushort_t* kc_a = (ushort_t*)(cb + (size_t)NB * 20447232);          // NB*3,145,728
  ushort_t* kc_b = (ushort_t*)(cb + (size_t)NB * 23592960);          // NB*1,572,864
  ushort_t* kc_c = (ushort_t*)(cb + (size_t)NB * 25165824);          // NB*  786,432
  ushort_t* kvxT = (ushort_t*)(cb + (size_t)NB * 25952256);          // NB*  122,880
  ushort_t* x8   = (ushort_t*)(cb + (size_t)NB * 26075136);          // NB*  786,432
  // aliases: kvp/ksp live in k16's space (k16 dead after pool stage 1);
  //          ao16 lives in xb16's space (xb16 dead after gemm_qkv/gemm_v).
  float* kvp = (float*)k16;
  float* ksp = (float*)((unsigned char*)k16 + (size_t)NB * 3145728);
  ushort_t* ao16 = xb16;

  const ushort_t* pWt = Wt6;
  const ushort_t* eWt = Wt6 + 3 * 4096;
  const size_t SB = (size_t)N_ * DIM_;

  transpose_w_bf16<<<dim3(24, 24), 256, 0, stream>>>(Wq, WqkvT);
  transpose_w_bf16<<<dim3(24, 24), 256, 0, stream>>>(Wk, WqkvT + 768 * 768);
  transpose_w_bf16<<<dim3(24, 24), 256, 0, stream>>>(Wv, WqkvT + 2 * 768 * 768);
  transpose_w_bf16<<<dim3(24, 24), 256, 0, stream>>>(Wo, WoT);
  transpose64_bf16<<<6, 256, 0, stream>>>(pW, eW, Wt6);

  const ushort_t* WvT = WqkvT + 2 * 768 * 768;

  for (int b0 = 0; b0 < B_; b0 += NB) {
    const float* xc = x + (size_t)b0 * SB;
    float* oc = outp + (size_t)b0 * SB;

    conv_f32_bf16<<<NB * 3072, 256, 0, stream>>>(xc, xb16);
    pool8_x<<<NB * 192, 256, 0, stream>>>(xb16, x8);
    gemm_qkv<<<dim3(12, NB * 32), 256, 0, stream>>>(xb16, WqkvT, q16, k16);
    gemm_v<<<dim3(6, NB * 4), 256, 0, stream>>>(x8, WvT, vc);

    // k-path pooling (MFMA), output [bb][h][n][64] bf16
    pool_mfma<<<dim3(16, 12, NB), 256, 0, stream>>>(k16, kc_a, 2048, 64L, 768,
        3145728L, 1572864L, pWt, pb, pg, pbe);
    pool_mfma<<<dim3(8, 12, NB), 256, 0, stream>>>(kc_a, kc_b, 1024, 131072L, 64,
        1572864L, 786432L, pWt + 4096, pb + 64, pg + 64, pbe + 64);
    pool_mfma<<<dim3(4, 12, NB), 256, 0, stream>>>(kc_b, kc_c, 512, 65536L, 64,
        786432L, 393216L, pWt + 8192, pb + 128, pg + 128, pbe + 128);

    kv_part_kernel<<<dim3(12, 16, NB), 256, 0, stream>>>(kc_c, vc, kvp, ksp);
    kv_reduce_t<<<dim3(240, NB), 256, 0, stream>>>(kvp, ksp, kvxT);

    attn_exp_mfma<<<dim3(32, 12, NB), 256, 0, stream>>>(q16, kvxT, eWt,
                                                        eb, eg, ebe, ao16);

    gemm_out<<<dim3(6, NB * 32), 256, 0, stream>>>(ao16, WoT, bo, oc);
  }
}

// Round 6
// 581.303 us; speedup vs baseline: 2.5213x; 1.0089x over previous
//
#include <hip/hip_runtime.h>
#include <math.h>

#define B_   8
#define N_   4096
#define DIM_ 768
#define H_   12
#define D_   64

typedef unsigned short ushort_t;
typedef unsigned int uint_t;
typedef __attribute__((ext_vector_type(8))) short short8;
typedef __attribute__((ext_vector_type(4))) float f32x4;

// ---------------------------------------------------------------------------
// helpers
// ---------------------------------------------------------------------------
// gelu with Abramowitz-Stegun 7.1.26 erf (|err| <= 1.5e-7, branch-free)
__device__ __forceinline__ float gelu_exact(float z) {
  const float ax = fabsf(z) * 0.70710678118654752440f;
  const float t  = __builtin_amdgcn_rcpf(1.f + 0.3275911f * ax);
  float poly = ((((1.061405429f * t - 1.453152027f) * t + 1.421413741f) * t
                 - 0.284496736f) * t + 0.254829592f) * t;
  const float erfax = 1.f - poly * __expf(-ax * ax);
  const float erfv = __builtin_copysignf(erfax, z);
  return 0.5f * z * (1.f + erfv);
}

__device__ __forceinline__ ushort_t f2bf(float f) {
  union { float f; unsigned u; } x; x.f = f;
  unsigned r = x.u + 0x7FFFu + ((x.u >> 16) & 1u);   // RNE
  return (ushort_t)(r >> 16);
}

__device__ __forceinline__ float bf2f(ushort_t h) {
  union { unsigned u; float f; } x; x.u = ((unsigned)h) << 16;
  return x.f;
}

__device__ __forceinline__ void gl_lds16(const ushort_t* g, ushort_t* l) {
  __builtin_amdgcn_global_load_lds(
      (const __attribute__((address_space(1))) void*)g,
      (__attribute__((address_space(3))) void*)l, 16, 0, 0);
}

// ---------------------------------------------------------------------------
// 768x768 fp32 -> bf16 transposed copy (dst[n][k] = src[k][n])
// ---------------------------------------------------------------------------
__global__ __launch_bounds__(256) void transpose_w_bf16(
    const float* __restrict__ src, ushort_t* __restrict__ dst)
{
  __shared__ float t[32][33];
  const int lx = threadIdx.x & 31, ly = threadIdx.x >> 5;
  const int bx = blockIdx.x * 32;
  const int by = blockIdx.y * 32;
  #pragma unroll
  for (int j = 0; j < 32; j += 8)
    t[ly + j][lx] = src[(size_t)(by + ly + j) * 768 + bx + lx];
  __syncthreads();
  #pragma unroll
  for (int j = 0; j < 32; j += 8)
    dst[(size_t)(bx + ly + j) * 768 + by + lx] = f2bf(t[lx][ly + j]);
}

// 6x 64x64 transpose to bf16: dst[m][c][d] = src_m[d][c]; m<3 pool, else exp
__global__ __launch_bounds__(256) void transpose64_bf16(
    const float* __restrict__ pW, const float* __restrict__ eW,
    ushort_t* __restrict__ dst)
{
  const int m = blockIdx.x;
  const float* src = (m < 3) ? (pW + m * 4096) : (eW + (m - 3) * 4096);
  ushort_t* o = dst + m * 4096;
  for (int i = threadIdx.x; i < 4096; i += 256) {
    const int r = i >> 6, c = i & 63;
    o[c * 64 + r] = f2bf(src[r * 64 + c]);
  }
}

__global__ __launch_bounds__(256) void conv_f32_bf16(
    const float* __restrict__ src, ushort_t* __restrict__ dst)
{
  const int i = blockIdx.x * 256 + threadIdx.x;
  float4 f = ((const float4*)src)[i];
  ushort4 o;
  o.x = f2bf(f.x); o.y = f2bf(f.y); o.z = f2bf(f.z); o.w = f2bf(f.w);
  ((ushort4*)dst)[i] = o;
}

// ---------------------------------------------------------------------------
// x pooled by 8 tokens: x8[r][c] = mean_{j<8} xb[8r+j][c], bf16. grid (NB*192)
// ---------------------------------------------------------------------------
__global__ __launch_bounds__(256) void pool8_x(
    const ushort_t* __restrict__ xb, ushort_t* __restrict__ x8)
{
  const int idx = blockIdx.x * 256 + threadIdx.x;   // < NB*512*96
  const int r = idx / 96, gc = idx - r * 96;
  const ushort_t* p = xb + (size_t)(8 * r) * 768 + gc * 8;
  float s[8] = {};
  #pragma unroll
  for (int j = 0; j < 8; ++j) {
    short8 v = *(const short8*)(p + (size_t)j * 768);
    #pragma unroll
    for (int e = 0; e < 8; ++e) s[e] += bf2f((ushort_t)v[e]);
  }
  short8 o;
  #pragma unroll
  for (int e = 0; e < 8; ++e) o[e] = (short)f2bf(0.125f * s[e]);
  *(short8*)(x8 + (size_t)r * 768 + gc * 8) = o;
}

// ---------------------------------------------------------------------------
// bf16 MFMA GEMM mainloop: 128x128 tile, BK=32, 4 waves 2x2, 4x4 16x16 each.
// Single-buffer (R0-proven) + bijective XCD chunk swizzle (R1-proven).
// ---------------------------------------------------------------------------
#define GEMM_MAINLOOP(A, Bt, K)                                               \
  __shared__ ushort_t As[128 * 32];                                           \
  __shared__ ushort_t Bs[128 * 32];                                           \
  const int tid = threadIdx.x;                                                \
  const int nwg_ = (int)(gridDim.x * gridDim.y);                              \
  const int wgid0_ = (int)(blockIdx.y * gridDim.x + blockIdx.x);              \
  const int wgid_ = (wgid0_ & 7) * (nwg_ >> 3) + (wgid0_ >> 3);               \
  const int row0 = (wgid_ / (int)gridDim.x) * 128;                            \
  const int col0 = (wgid_ % (int)gridDim.x) * 128;                            \
  const int sr = tid >> 2;                                                    \
  const int sk = (tid & 3) * 8;                                               \
  const ushort_t* Ag0 = (A) + (size_t)(row0 + sr) * (K) + sk;                 \
  const ushort_t* Ag1 = Ag0 + (size_t)64 * (K);                               \
  const ushort_t* Bg0 = (Bt) + (size_t)(col0 + sr) * (K) + sk;                \
  const ushort_t* Bg1 = Bg0 + (size_t)64 * (K);                               \
  ushort_t* Asw = As + (tid >> 6) * 512;                                      \
  ushort_t* Bsw = Bs + (tid >> 6) * 512;                                      \
  const int w = tid >> 6, lane = tid & 63;                                    \
  const int wm = w >> 1, wn = w & 1;                                          \
  const int qd = lane >> 4, l15 = lane & 15;                                  \
  const int aoff = (wm * 64 + l15) * 32 + qd * 8;                             \
  const int boff = (wn * 64 + l15) * 32 + qd * 8;                             \
  f32x4 acc[4][4] = {};                                                       \
  for (int k0 = 0; k0 < (K); k0 += 32) {                                      \
    __syncthreads();                                                          \
    gl_lds16(Ag0 + k0, Asw);                                                  \
    gl_lds16(Ag1 + k0, Asw + 2048);                                           \
    gl_lds16(Bg0 + k0, Bsw);                                                  \
    gl_lds16(Bg1 + k0, Bsw + 2048);                                           \
    __syncthreads();                                                          \
    short8 af[4], bfr[4];                                                     \
    _Pragma("unroll")                                                         \
    for (int mt = 0; mt < 4; ++mt) af[mt] = *(const short8*)&As[aoff + mt * 512]; \
    _Pragma("unroll")                                                         \
    for (int nt = 0; nt < 4; ++nt) bfr[nt] = *(const short8*)&Bs[boff + nt * 512]; \
    _Pragma("unroll")                                                         \
    for (int mt = 0; mt < 4; ++mt)                                            \
      _Pragma("unroll")                                                       \
      for (int nt = 0; nt < 4; ++nt)                                          \
        acc[mt][nt] = __builtin_amdgcn_mfma_f32_16x16x32_bf16(                \
            af[mt], bfr[nt], acc[mt][nt], 0, 0, 0);                           \
  }

// QKV (q,k only): q bf16 elu+1, k bf16 elu+1. grid (12, NB*32)
__global__ __launch_bounds__(256) void gemm_qkv(
    const ushort_t* __restrict__ A, const ushort_t* __restrict__ Bt,
    ushort_t* __restrict__ qo, ushort_t* __restrict__ ko)
{
  GEMM_MAINLOOP(A, Bt, 768)
  const int sel = col0 / 768;
  const int colbase = (col0 % 768) + wn * 64;
  ushort_t* o = (sel == 0) ? qo : ko;
  #pragma unroll
  for (int mt = 0; mt < 4; ++mt) {
    #pragma unroll
    for (int nt = 0; nt < 4; ++nt) {
      const int cg = colbase + nt * 16 + l15;
      #pragma unroll
      for (int r = 0; r < 4; ++r) {
        const int rg = row0 + wm * 64 + mt * 16 + qd * 4 + r;
        const float vv = acc[mt][nt][r];
        const float e = (vv > 0.f) ? vv + 1.f : __expf(vv);
        o[(size_t)rg * 768 + cg] = f2bf(e);
      }
    }
  }
}

// V GEMM on pooled x8: vc[b][h][n][64] f32 = x8 @ WvT. grid (6, NB*4)
__global__ __launch_bounds__(256) void gemm_v(
    const ushort_t* __restrict__ A, const ushort_t* __restrict__ Bt,
    float* __restrict__ vco)
{
  GEMM_MAINLOOP(A, Bt, 768)
  #pragma unroll
  for (int mt = 0; mt < 4; ++mt) {
    #pragma unroll
    for (int nt = 0; nt < 4; ++nt) {
      const int cg = col0 + wn * 64 + nt * 16 + l15;
      const int hh = cg >> 6, d = cg & 63;
      #pragma unroll
      for (int r = 0; r < 4; ++r) {
        const int rg = row0 + wm * 64 + mt * 16 + qd * 4 + r;
        const int b = rg >> 9, n = rg & 511;
        vco[(((size_t)b * 12 + hh) * 512 + n) * 64 + d] = acc[mt][nt][r];
      }
    }
  }
}

// Output GEMM + bias. grid (6, NB*32)
__global__ __launch_bounds__(256) void gemm_out(
    const ushort_t* __restrict__ A, const ushort_t* __restrict__ Bt,
    const float* __restrict__ bo, float* __restrict__ C)
{
  GEMM_MAINLOOP(A, Bt, 768)
  #pragma unroll
  for (int mt = 0; mt < 4; ++mt) {
    #pragma unroll
    for (int nt = 0; nt < 4; ++nt) {
      const int cg = col0 + wn * 64 + nt * 16 + l15;
      #pragma unroll
      for (int r = 0; r < 4; ++r) {
        const int rg = row0 + wm * 64 + mt * 16 + qd * 4 + r;
        C[(size_t)rg * 768 + cg] = acc[mt][nt][r] + bo[cg];
      }
    }
  }
}

// ---------------------------------------------------------------------------
// Fused k-pool chain + kv partials. grid (16, 12, NB), 256 thr.
// Block: 256 k16 tokens -> pool2+MLP -> 128 -> pool2+MLP -> 64 -> pool2+MLP
// -> 32 t3 tokens (all in LDS) -> kv partial chunk (32 tokens).
// Replaces pool_mfma x3 + kv_part: intermediates never touch HBM.
// ---------------------------------------------------------------------------
__device__ __forceinline__ void mlp_stage(
    const ushort_t* __restrict__ inb, ushort_t* __restrict__ outb,
    const ushort_t* __restrict__ Wls, const float* __restrict__ bias,
    const float* __restrict__ g, const float* __restrict__ be,
    int rowbase, int ntiles, int tid)
{
  if (ntiles == 0) return;   // wave-uniform
  const int lane = tid & 63, quad = lane >> 4, l15 = lane & 15;
  float bv[4], gv[4], bev[4];
  #pragma unroll
  for (int nt = 0; nt < 4; ++nt) {
    const int c = nt * 16 + l15;
    bv[nt] = bias[c]; gv[nt] = g[c]; bev[nt] = be[c];
  }
  f32x4 a2[2][4];
  #pragma unroll
  for (int mt = 0; mt < 2; ++mt)
    #pragma unroll
    for (int nt = 0; nt < 4; ++nt)
      a2[mt][nt] = f32x4{bv[nt], bv[nt], bv[nt], bv[nt]};

  #pragma unroll
  for (int ks = 0; ks < 2; ++ks) {
    short8 af[2], bfr[4];
    #pragma unroll
    for (int mt = 0; mt < 2; ++mt)
      if (mt < ntiles)
        af[mt] = *(const short8*)&inb[(rowbase + mt * 16 + l15) * 72 + ks * 32 + quad * 8];
    #pragma unroll
    for (int nt = 0; nt < 4; ++nt)
      bfr[nt] = *(const short8*)&Wls[(nt * 16 + l15) * 72 + ks * 32 + quad * 8];
    #pragma unroll
    for (int mt = 0; mt < 2; ++mt)
      if (mt < ntiles)
        #pragma unroll
        for (int nt = 0; nt < 4; ++nt)
          a2[mt][nt] = __builtin_amdgcn_mfma_f32_16x16x32_bf16(af[mt], bfr[nt], a2[mt][nt], 0, 0, 0);
  }

  #pragma unroll
  for (int mt = 0; mt < 2; ++mt) {
    if (mt >= ntiles) continue;
    #pragma unroll
    for (int r = 0; r < 4; ++r) {
      float sum = a2[mt][0][r] + a2[mt][1][r] + a2[mt][2][r] + a2[mt][3][r];
      #pragma unroll
      for (int m = 1; m < 16; m <<= 1) sum += __shfl_xor(sum, m, 64);
      const float mu = sum * 0.015625f;
      float dv[4], var = 0.f;
      #pragma unroll
      for (int nt = 0; nt < 4; ++nt) { dv[nt] = a2[mt][nt][r] - mu; var += dv[nt] * dv[nt]; }
      #pragma unroll
      for (int m = 1; m < 16; m <<= 1) var += __shfl_xor(var, m, 64);
      const float rstd = rsqrtf(var * 0.015625f + 1e-5f);
      const int rl = rowbase + mt * 16 + quad * 4 + r;
      #pragma unroll
      for (int nt = 0; nt < 4; ++nt) {
        const float z = dv[nt] * rstd * gv[nt] + bev[nt];
        outb[rl * 72 + nt * 16 + l15] = f2bf(gelu_exact(z));
      }
    }
  }
}

__device__ __forceinline__ void pool_pairs(
    const ushort_t* __restrict__ inb, ushort_t* __restrict__ outb,
    int outRows, int tid)
{
  for (int idx = tid; idx < outRows * 8; idx += 256) {
    const int rl = idx >> 3, ch = idx & 7;
    short8 a = *(const short8*)&inb[(2 * rl) * 72 + ch * 8];
    short8 b = *(const short8*)&inb[(2 * rl + 1) * 72 + ch * 8];
    short8 o;
    #pragma unroll
    for (int e = 0; e < 8; ++e)
      o[e] = (short)f2bf(0.5f * (bf2f((ushort_t)a[e]) + bf2f((ushort_t)b[e])));
    *(short8*)&outb[rl * 72 + ch * 8] = o;
  }
}

__global__ __launch_bounds__(256) void pool_kv_fused(
    const ushort_t* __restrict__ k16, const float* __restrict__ vc,
    const ushort_t* __restrict__ pWt,
    const float* __restrict__ pb, const float* __restrict__ pg,
    const float* __restrict__ pbe,
    float* __restrict__ kvp, float* __restrict__ ksp)
{
  __shared__ ushort_t Wl[3 * 64 * 72];   // 27.0 KB
  __shared__ ushort_t bufA[128 * 72];    // 18.0 KB
  __shared__ ushort_t bufB[128 * 72];    // 18.0 KB
  __shared__ float    vs[32 * 64];       //  8.0 KB
  const int tid = threadIdx.x;
  const int x = blockIdx.x;      // 0..15: t1 rows 128x.., t3 chunk x
  const int h = blockIdx.y;
  const int bb = blockIdx.z;
  const ushort_t* kin = k16 + (size_t)bb * 3145728;
  const float* vp = vc + (size_t)bb * 393216 + ((size_t)h * 512 + x * 32) * 64;

  // stage weights (3 x 64x64 -> rows padded to 72)
  {
    const uint_t* ws = (const uint_t*)pWt;
    for (int i = tid; i < 6144; i += 256) {
      const int s = i >> 11, rem = i & 2047, r = rem >> 5, c = rem & 31;
      ((uint_t*)(Wl + (s * 64 + r) * 72))[c] = ws[i];
    }
  }
  // stage pooled k16 (mean of token pairs) into bufA rows 0..127
  #pragma unroll
  for (int j = 0; j < 4; ++j) {
    const int idx = j * 256 + tid;
    const int rl = idx >> 3, ch = idx & 7;
    const ushort_t* p = kin + (size_t)h * 64 + (size_t)(2 * (x * 128 + rl)) * 768 + ch * 8;
    short8 a = *(const short8*)p;
    short8 b2 = *(const short8*)(p + 768);
    short8 o;
    #pragma unroll
    for (int e = 0; e < 8; ++e)
      o[e] = (short)f2bf(0.5f * (bf2f((ushort_t)a[e]) + bf2f((ushort_t)b2[e])));
    *(short8*)&bufA[rl * 72 + ch * 8] = o;
  }
  // stage vc chunk (32 x 64 f32)
  #pragma unroll
  for (int i = 0; i < 2; ++i)
    ((float4*)vs)[tid + 256 * i] = ((const float4*)vp)[tid + 256 * i];
  __syncthreads();

  const int w = tid >> 6;
  // stage 1: 128 rows
  mlp_stage(bufA, bufB, Wl, pb, pg, pbe, w * 32, 2, tid);
  __syncthreads();
  pool_pairs(bufB, bufA, 64, tid);
  __syncthreads();
  // stage 2: 64 rows
  mlp_stage(bufA, bufB, Wl + 64 * 72, pb + 64, pg + 64, pbe + 64, w * 16, 1, tid);
  __syncthreads();
  pool_pairs(bufB, bufA, 32, tid);
  __syncthreads();
  // stage 3: 32 rows (waves 0,1 active)
  mlp_stage(bufA, bufB, Wl + 128 * 72, pb + 128, pg + 128, pbe + 128,
            w * 16, (w < 2) ? 1 : 0, tid);
  __syncthreads();

  // kv partial over the 32 t3 tokens in bufB
  const int e = tid & 63;
  const int dg = tid >> 6;
  float acc[16] = {};
  float accs = 0.f;
  for (int nn = 0; nn < 32; ++nn) {
    const float vv = vs[nn * 64 + e];
    #pragma unroll
    for (int j = 0; j < 16; ++j)
      acc[j] += bf2f(bufB[nn * 72 + dg * 16 + j]) * vv;
    if (tid < 64) accs += bf2f(bufB[nn * 72 + tid]);
  }
  float* o = kvp + (size_t)bb * 786432 + ((size_t)h * 16 + x) * 4096;
  #pragma unroll
  for (int j = 0; j < 16; ++j)
    o[(dg * 16 + j) * 64 + e] = acc[j];
  if (tid < 64) ksp[(size_t)bb * 12288 + (h * 16 + x) * 64 + tid] = accs;
}

// reduce partials -> kvxT bf16 [bb][h][80][64]: rows 0..63 = kv^T (e,d),
// row 64 = ksum, rows 65..79 = 0. grid (240, NB).
__global__ __launch_bounds__(256) void kv_reduce_t(
    const float* __restrict__ kvp, const float* __restrict__ ksp,
    ushort_t* __restrict__ kvxT)
{
  const int bb = blockIdx.y;
  kvp  += (size_t)bb * 786432;
  ksp  += (size_t)bb * 12288;
  kvxT += (size_t)bb * 61440;
  const int idx = blockIdx.x * 256 + threadIdx.x;   // < 61440
  const int h = idx / 5120;
  const int rem = idx - h * 5120;
  const int er = rem >> 6, d = rem & 63;
  const float scale = 0.044194173824159216f;  // 1/sqrt(512)
  float val = 0.f;
  if (er < 64) {
    float s = 0.f;
    #pragma unroll
    for (int c = 0; c < 16; ++c) s += kvp[((size_t)h * 16 + c) * 4096 + d * 64 + er];
    val = s * scale;
  } else if (er == 64) {
    float s = 0.f;
    #pragma unroll
    for (int c = 0; c < 16; ++c) s += ksp[(h * 16 + c) * 64 + d];
    val = s * scale;
  }
  kvxT[idx] = f2bf(val);
}

// ---------------------------------------------------------------------------
// Fused MFMA attention-apply + 3 expansion MLPs.
// grid (32, 12, NB): 128 tokens x 1 head per block. Writes bf16 (n,768).
// ---------------------------------------------------------------------------
__global__ __launch_bounds__(256) void attn_exp_mfma(
    const ushort_t* __restrict__ q16, const ushort_t* __restrict__ kvxT,
    const ushort_t* __restrict__ eWt,
    const float* __restrict__ eb, const float* __restrict__ eg,
    const float* __restrict__ ebe, ushort_t* __restrict__ out16)
{
  __shared__ ushort_t Wl[3 * 64 * 72];
  __shared__ ushort_t tl[128 * 72];
  const int tid = threadIdx.x;
  const int h = blockIdx.y;
  const int bb = blockIdx.z;
  const int row0 = blockIdx.x * 128;
  q16   += (size_t)bb * 3145728;
  out16 += (size_t)bb * 3145728;
  const ushort_t* kvx = kvxT + (size_t)bb * 61440 + (size_t)h * 5120;

  {
    const uint_t* ws = (const uint_t*)eWt;
    for (int i = tid; i < 6144; i += 256) {
      const int s = i >> 11, rem = i & 2047, r = rem >> 5, c = rem & 31;
      ((uint_t*)(Wl + (s * 64 + r) * 72))[c] = ws[i];
    }
  }
  __syncthreads();

  const int w = tid >> 6, lane = tid & 63;
  const int quad = lane >> 4, l15 = lane & 15;

  // attention matmul incl. denominator column
  f32x4 acc[2][5] = {};
  #pragma unroll
  for (int ks = 0; ks < 2; ++ks) {
    short8 af[2], bfr[5];
    #pragma unroll
    for (int mt = 0; mt < 2; ++mt) {
      const int rg = row0 + w * 32 + mt * 16 + l15;
      af[mt] = *(const short8*)(q16 + (size_t)rg * 768 + h * 64 + ks * 32 + quad * 8);
    }
    #pragma unroll
    for (int nt = 0; nt < 5; ++nt)
      bfr[nt] = *(const short8*)(kvx + (nt * 16 + l15) * 64 + ks * 32 + quad * 8);
    #pragma unroll
    for (int mt = 0; mt < 2; ++mt)
      #pragma unroll
      for (int nt = 0; nt < 5; ++nt)
        acc[mt][nt] = __builtin_amdgcn_mfma_f32_16x16x32_bf16(af[mt], bfr[nt], acc[mt][nt], 0, 0, 0);
  }

  float t[2][4][4];
  #pragma unroll
  for (int mt = 0; mt < 2; ++mt)
    #pragma unroll
    for (int r = 0; r < 4; ++r) {
      const float den = __shfl(acc[mt][4][r], lane & 48, 64) + 1e-6f;
      const float inv = __builtin_amdgcn_rcpf(den);
      #pragma unroll
      for (int nt = 0; nt < 4; ++nt)
        t[mt][nt][r] = acc[mt][nt][r] * inv;
    }

  // 3 expansion stages (s = 2, 1, 0)
  for (int s = 2; s >= 0; --s) {
    __syncthreads();
    #pragma unroll
    for (int mt = 0; mt < 2; ++mt)
      #pragma unroll
      for (int nt = 0; nt < 4; ++nt)
        #pragma unroll
        for (int r = 0; r < 4; ++r)
          tl[(w * 32 + mt * 16 + quad * 4 + r) * 72 + nt * 16 + l15] = f2bf(t[mt][nt][r]);
    __syncthreads();

    float bv[4], gv[4], bev[4];
    #pragma unroll
    for (int nt = 0; nt < 4; ++nt) {
      const int c = s * 64 + nt * 16 + l15;
      bv[nt] = eb[c]; gv[nt] = eg[c]; bev[nt] = ebe[c];
    }
    f32x4 a2[2][4];
    #pragma unroll
    for (int mt = 0; mt < 2; ++mt)
      #pragma unroll
      for (int nt = 0; nt < 4; ++nt)
        a2[mt][nt] = f32x4{bv[nt], bv[nt], bv[nt], bv[nt]};

    #pragma unroll
    for (int ks = 0; ks < 2; ++ks) {
      short8 af[2], bfr[4];
      #pragma unroll
      for (int mt = 0; mt < 2; ++mt)
        af[mt] = *(const short8*)&tl[(w * 32 + mt * 16 + l15) * 72 + ks * 32 + quad * 8];
      #pragma unroll
      for (int nt = 0; nt < 4; ++nt)
        bfr[nt] = *(const short8*)&Wl[(s * 64 + nt * 16 + l15) * 72 + ks * 32 + quad * 8];
      #pragma unroll
      for (int mt = 0; mt < 2; ++mt)
        #pragma unroll
        for (int nt = 0; nt < 4; ++nt)
          a2[mt][nt] = __builtin_amdgcn_mfma_f32_16x16x32_bf16(af[mt], bfr[nt], a2[mt][nt], 0, 0, 0);
    }

    #pragma unroll
    for (int mt = 0; mt < 2; ++mt)
      #pragma unroll
      for (int r = 0; r < 4; ++r) {
        float sum = a2[mt][0][r] + a2[mt][1][r] + a2[mt][2][r] + a2[mt][3][r];
        #pragma unroll
        for (int m = 1; m < 16; m <<= 1) sum += __shfl_xor(sum, m, 64);
        const float mu = sum * 0.015625f;
        float dv[4], var = 0.f;
        #pragma unroll
        for (int nt = 0; nt < 4; ++nt) { dv[nt] = a2[mt][nt][r] - mu; var += dv[nt] * dv[nt]; }
        #pragma unroll
        for (int m = 1; m < 16; m <<= 1) var += __shfl_xor(var, m, 64);
        const float rstd = rsqrtf(var * 0.015625f + 1e-5f);
        #pragma unroll
        for (int nt = 0; nt < 4; ++nt) {
          const float z = dv[nt] * rstd * gv[nt] + bev[nt];
          t[mt][nt][r] = gelu_exact(z);
        }
      }
  }

  #pragma unroll
  for (int mt = 0; mt < 2; ++mt)
    #pragma unroll
    for (int nt = 0; nt < 4; ++nt)
      #pragma unroll
      for (int r = 0; r < 4; ++r) {
        const int rg = row0 + w * 32 + mt * 16 + quad * 4 + r;
        out16[(size_t)rg * 768 + h * 64 + nt * 16 + l15] = f2bf(t[mt][nt][r]);
      }
}

// ---------------------------------------------------------------------------
// launch
// ---------------------------------------------------------------------------
extern "C" void kernel_launch(void* const* d_in, const int* in_sizes, int n_in,
                              void* d_out, int out_size, void* d_ws, size_t ws_size,
                              hipStream_t stream)
{
  const float* x   = (const float*)d_in[0];
  const float* Wq  = (const float*)d_in[1];
  const float* Wk  = (const float*)d_in[2];
  const float* Wv  = (const float*)d_in[3];
  const float* pW  = (const float*)d_in[4];
  const float* pb  = (const float*)d_in[5];
  const float* pg  = (const float*)d_in[6];
  const float* pbe = (const float*)d_in[7];
  const float* eW  = (const float*)d_in[8];
  const float* eb  = (const float*)d_in[9];
  const float* eg  = (const float*)d_in[10];
  const float* ebe = (const float*)d_in[11];
  const float* Wo  = (const float*)d_in[12];
  const float* bo  = (const float*)d_in[13];
  float* outp = (float*)d_out;

  // ---- workspace: fixed weight area + NB-batch chunk area ----
  unsigned char* wsb = (unsigned char*)d_ws;
  ushort_t* WqkvT = (ushort_t*)(wsb + 0);              // 3,538,944
  ushort_t* WoT   = (ushort_t*)(wsb + 3538944);        // 1,179,648
  ushort_t* Wt6   = (ushort_t*)(wsb + 4718592);        //    49,152
  const size_t CB   = 4767744;                         // chunk base
  const size_t PERB = 26861568;                        // bytes per batch

  int NB;
  if      (ws_size >= CB + 8 * PERB) NB = 8;
  else if (ws_size >= CB + 4 * PERB) NB = 4;
  else if (ws_size >= CB + 2 * PERB) NB = 2;
  else if (ws_size >= CB + 1 * PERB) NB = 1;
  else return;

  unsigned char* cb = wsb + CB;
  ushort_t* xb16 = (ushort_t*)(cb);                                  // NB*6,291,456
  ushort_t* q16  = (ushort_t*)(cb + (size_t)NB *  6291456);          // NB*6,291,456
  ushort_t* k16  = (ushort_t*)(cb + (size_t)NB * 12582912);          // NB*6,291,456
  float*    vc   = (float*)   (cb + (size_t)NB * 18874368);          // NB*1,572,864
  ushort_t* kc_a = (ushort_t*)(cb + (size_t)NB * 20447232);          // NB*3,145,728 (now kvp)
  ushort_t* kc_b = (ushort_t*)(cb + (size_t)NB * 23592960);          // NB*1,572,864 (now ksp)
  ushort_t* kvxT = (ushort_t*)(cb + (size_t)NB * 25952256);          // NB*  122,880
  ushort_t* x8   = (ushort_t*)(cb + (size_t)NB * 26075136);          // NB*  786,432
  // aliases: kvp/ksp live in kc_a/kc_b (dead since pool chain fused);
  //          ao16 lives in xb16's space (xb16 dead after gemm_qkv/gemm_v).
  float* kvp = (float*)kc_a;
  float* ksp = (float*)kc_b;
  ushort_t* ao16 = xb16;

  const ushort_t* pWt = Wt6;
  const ushort_t* eWt = Wt6 + 3 * 4096;
  const size_t SB = (size_t)N_ * DIM_;

  transpose_w_bf16<<<dim3(24, 24), 256, 0, stream>>>(Wq, WqkvT);
  transpose_w_bf16<<<dim3(24, 24), 256, 0, stream>>>(Wk, WqkvT + 768 * 768);
  transpose_w_bf16<<<dim3(24, 24), 256, 0, stream>>>(Wv, WqkvT + 2 * 768 * 768);
  transpose_w_bf16<<<dim3(24, 24), 256, 0, stream>>>(Wo, WoT);
  transpose64_bf16<<<6, 256, 0, stream>>>(pW, eW, Wt6);

  const ushort_t* WvT = WqkvT + 2 * 768 * 768;

  for (int b0 = 0; b0 < B_; b0 += NB) {
    const float* xc = x + (size_t)b0 * SB;
    float* oc = outp + (size_t)b0 * SB;

    conv_f32_bf16<<<NB * 3072, 256, 0, stream>>>(xc, xb16);
    pool8_x<<<NB * 192, 256, 0, stream>>>(xb16, x8);
    gemm_qkv<<<dim3(12, NB * 32), 256, 0, stream>>>(xb16, WqkvT, q16, k16);
    gemm_v<<<dim3(6, NB * 4), 256, 0, stream>>>(x8, WvT, vc);

    pool_kv_fused<<<dim3(16, 12, NB), 256, 0, stream>>>(k16, vc, pWt,
                                                        pb, pg, pbe, kvp, ksp);
    kv_reduce_t<<<dim3(240, NB), 256, 0, stream>>>(kvp, ksp, kvxT);

    attn_exp_mfma<<<dim3(32, 12, NB), 256, 0, stream>>>(q16, kvxT, eWt,
                                                        eb, eg, ebe, ao16);

    gemm_out<<<dim3(6, NB * 32), 256, 0, stream>>>(ao16, WoT, bo, oc);
  }
}

// Round 7
// 566.606 us; speedup vs baseline: 2.5867x; 1.0259x over previous
//
#include <hip/hip_runtime.h>
#include <math.h>

#define B_   8
#define N_   4096
#define DIM_ 768
#define H_   12
#define D_   64

typedef unsigned short ushort_t;
typedef unsigned int uint_t;
typedef __attribute__((ext_vector_type(8))) short short8;
typedef __attribute__((ext_vector_type(4))) float f32x4;

// ---------------------------------------------------------------------------
// helpers
// ---------------------------------------------------------------------------
// gelu with Abramowitz-Stegun 7.1.26 erf (|err| <= 1.5e-7, branch-free)
__device__ __forceinline__ float gelu_exact(float z) {
  const float ax = fabsf(z) * 0.70710678118654752440f;
  const float t  = __builtin_amdgcn_rcpf(1.f + 0.3275911f * ax);
  float poly = ((((1.061405429f * t - 1.453152027f) * t + 1.421413741f) * t
                 - 0.284496736f) * t + 0.254829592f) * t;
  const float erfax = 1.f - poly * __expf(-ax * ax);
  const float erfv = __builtin_copysignf(erfax, z);
  return 0.5f * z * (1.f + erfv);
}

__device__ __forceinline__ ushort_t f2bf(float f) {
  union { float f; unsigned u; } x; x.f = f;
  unsigned r = x.u + 0x7FFFu + ((x.u >> 16) & 1u);   // RNE
  return (ushort_t)(r >> 16);
}

__device__ __forceinline__ float bf2f(ushort_t h) {
  union { unsigned u; float f; } x; x.u = ((unsigned)h) << 16;
  return x.f;
}

__device__ __forceinline__ void gl_lds16(const ushort_t* g, ushort_t* l) {
  __builtin_amdgcn_global_load_lds(
      (const __attribute__((address_space(1))) void*)g,
      (__attribute__((address_space(3))) void*)l, 16, 0, 0);
}

// ---------------------------------------------------------------------------
// 768x768 fp32 -> bf16 transposed copy (dst[n][k] = src[k][n])
// ---------------------------------------------------------------------------
__global__ __launch_bounds__(256) void transpose_w_bf16(
    const float* __restrict__ src, ushort_t* __restrict__ dst)
{
  __shared__ float t[32][33];
  const int lx = threadIdx.x & 31, ly = threadIdx.x >> 5;
  const int bx = blockIdx.x * 32;
  const int by = blockIdx.y * 32;
  #pragma unroll
  for (int j = 0; j < 32; j += 8)
    t[ly + j][lx] = src[(size_t)(by + ly + j) * 768 + bx + lx];
  __syncthreads();
  #pragma unroll
  for (int j = 0; j < 32; j += 8)
    dst[(size_t)(bx + ly + j) * 768 + by + lx] = f2bf(t[lx][ly + j]);
}

// 6x 64x64 transpose to bf16: dst[m][c][d] = src_m[d][c]; m<3 pool, else exp
__global__ __launch_bounds__(256) void transpose64_bf16(
    const float* __restrict__ pW, const float* __restrict__ eW,
    ushort_t* __restrict__ dst)
{
  const int m = blockIdx.x;
  const float* src = (m < 3) ? (pW + m * 4096) : (eW + (m - 3) * 4096);
  ushort_t* o = dst + m * 4096;
  for (int i = threadIdx.x; i < 4096; i += 256) {
    const int r = i >> 6, c = i & 63;
    o[c * 64 + r] = f2bf(src[r * 64 + c]);
  }
}

// ---------------------------------------------------------------------------
// Fused x f32->bf16 conversion + 8-token mean pool.
// grid (NB*512), 192 thr: block = one 8-token group (8x768).
// Thread t owns float4 column-chunk t (t<192) across the 8 rows.
// ---------------------------------------------------------------------------
__global__ __launch_bounds__(192) void conv_pool8(
    const float* __restrict__ src, ushort_t* __restrict__ dst,
    ushort_t* __restrict__ x8)
{
  const int g = blockIdx.x;
  const int t = threadIdx.x;
  const float4* s = (const float4*)(src + (size_t)g * 8 * 768);
  ushort4* d = (ushort4*)(dst + (size_t)g * 8 * 768);
  float4 sum = {0.f, 0.f, 0.f, 0.f};
  #pragma unroll
  for (int j = 0; j < 8; ++j) {
    float4 f = s[j * 192 + t];
    ushort4 o;
    o.x = f2bf(f.x); o.y = f2bf(f.y); o.z = f2bf(f.z); o.w = f2bf(f.w);
    d[j * 192 + t] = o;
    sum.x += f.x; sum.y += f.y; sum.z += f.z; sum.w += f.w;
  }
  ushort4 m;
  m.x = f2bf(0.125f * sum.x); m.y = f2bf(0.125f * sum.y);
  m.z = f2bf(0.125f * sum.z); m.w = f2bf(0.125f * sum.w);
  ((ushort4*)(x8 + (size_t)g * 768))[t] = m;
}

// ---------------------------------------------------------------------------
// bf16 MFMA GEMM mainloop: 128x128 tile, BK=64, 4 waves 2x2, 4x4 16x16 each.
// Single-buffer + XCD chunk swizzle (proven) + 8-slot XOR bank swizzle:
// LDS slot s of row r holds global 8-elem chunk (s ^ (r&7)) — applied on the
// per-lane GLOBAL source addr (LDS dest stays linear for global_load_lds),
// and inverted on the ds_read offsets (s1 = s0 ^ 32). Halves barrier count
// vs BK=32 (12 iters instead of 24).
// ---------------------------------------------------------------------------
#define GEMM_MAINLOOP(A, Bt, K)                                               \
  __shared__ ushort_t As[128 * 64];                                           \
  __shared__ ushort_t Bs[128 * 64];                                           \
  const int tid = threadIdx.x;                                                \
  const int nwg_ = (int)(gridDim.x * gridDim.y);                              \
  const int wgid0_ = (int)(blockIdx.y * gridDim.x + blockIdx.x);              \
  const int wgid_ = (wgid0_ & 7) * (nwg_ >> 3) + (wgid0_ >> 3);               \
  const int row0 = (wgid_ / (int)gridDim.x) * 128;                            \
  const int col0 = (wgid_ % (int)gridDim.x) * 128;                            \
  const ushort_t* pA[4]; const ushort_t* pB[4];                               \
  _Pragma("unroll")                                                           \
  for (int j = 0; j < 4; ++j) {                                               \
    const int g_ = tid + j * 256;                                             \
    const int rr = g_ >> 3, sc = g_ & 7;                                      \
    pA[j] = (A) + (size_t)(row0 + rr) * (K) + ((sc ^ (rr & 7)) << 3);         \
    pB[j] = (Bt) + (size_t)(col0 + rr) * (K) + ((sc ^ (rr & 7)) << 3);        \
  }                                                                           \
  const int w = tid >> 6, lane = tid & 63;                                    \
  const int stw = w * 512;                                                    \
  const int wm = w >> 1, wn = w & 1;                                          \
  const int qd = lane >> 4, l15 = lane & 15;                                  \
  const int s0 = ((qd ^ (l15 & 7)) << 3);                                     \
  const int abase = (wm * 64 + l15) * 64;                                     \
  const int bbase = (wn * 64 + l15) * 64;                                     \
  f32x4 acc[4][4] = {};                                                       \
  for (int k0 = 0; k0 < (K); k0 += 64) {                                      \
    __syncthreads();                                                          \
    _Pragma("unroll")                                                         \
    for (int j = 0; j < 4; ++j) gl_lds16(pA[j] + k0, As + j * 2048 + stw);    \
    _Pragma("unroll")                                                         \
    for (int j = 0; j < 4; ++j) gl_lds16(pB[j] + k0, Bs + j * 2048 + stw);    \
    __syncthreads();                                                          \
    short8 af[4], bfr[4];                                                     \
    _Pragma("unroll")                                                         \
    for (int mt = 0; mt < 4; ++mt) af[mt] = *(const short8*)&As[abase + mt * 1024 + s0]; \
    _Pragma("unroll")                                                         \
    for (int nt = 0; nt < 4; ++nt) bfr[nt] = *(const short8*)&Bs[bbase + nt * 1024 + s0]; \
    _Pragma("unroll")                                                         \
    for (int mt = 0; mt < 4; ++mt)                                            \
      _Pragma("unroll")                                                       \
      for (int nt = 0; nt < 4; ++nt)                                          \
        acc[mt][nt] = __builtin_amdgcn_mfma_f32_16x16x32_bf16(                \
            af[mt], bfr[nt], acc[mt][nt], 0, 0, 0);                           \
    _Pragma("unroll")                                                         \
    for (int mt = 0; mt < 4; ++mt) af[mt] = *(const short8*)&As[abase + mt * 1024 + (s0 ^ 32)]; \
    _Pragma("unroll")                                                         \
    for (int nt = 0; nt < 4; ++nt) bfr[nt] = *(const short8*)&Bs[bbase + nt * 1024 + (s0 ^ 32)]; \
    _Pragma("unroll")                                                         \
    for (int mt = 0; mt < 4; ++mt)                                            \
      _Pragma("unroll")                                                       \
      for (int nt = 0; nt < 4; ++nt)                                          \
        acc[mt][nt] = __builtin_amdgcn_mfma_f32_16x16x32_bf16(                \
            af[mt], bfr[nt], acc[mt][nt], 0, 0, 0);                           \
  }

// QKV (q,k only): q bf16 elu+1, k bf16 elu+1. grid (12, NB*32)
__global__ __launch_bounds__(256) void gemm_qkv(
    const ushort_t* __restrict__ A, const ushort_t* __restrict__ Bt,
    ushort_t* __restrict__ qo, ushort_t* __restrict__ ko)
{
  GEMM_MAINLOOP(A, Bt, 768)
  const int sel = col0 / 768;
  const int colbase = (col0 % 768) + wn * 64;
  ushort_t* o = (sel == 0) ? qo : ko;
  #pragma unroll
  for (int mt = 0; mt < 4; ++mt) {
    #pragma unroll
    for (int nt = 0; nt < 4; ++nt) {
      const int cg = colbase + nt * 16 + l15;
      #pragma unroll
      for (int r = 0; r < 4; ++r) {
        const int rg = row0 + wm * 64 + mt * 16 + qd * 4 + r;
        const float vv = acc[mt][nt][r];
        const float e = (vv > 0.f) ? vv + 1.f : __expf(vv);
        o[(size_t)rg * 768 + cg] = f2bf(e);
      }
    }
  }
}

// V GEMM on pooled x8: vc[b][h][n][64] f32 = x8 @ WvT. grid (6, NB*4)
__global__ __launch_bounds__(256) void gemm_v(
    const ushort_t* __restrict__ A, const ushort_t* __restrict__ Bt,
    float* __restrict__ vco)
{
  GEMM_MAINLOOP(A, Bt, 768)
  #pragma unroll
  for (int mt = 0; mt < 4; ++mt) {
    #pragma unroll
    for (int nt = 0; nt < 4; ++nt) {
      const int cg = col0 + wn * 64 + nt * 16 + l15;
      const int hh = cg >> 6, d = cg & 63;
      #pragma unroll
      for (int r = 0; r < 4; ++r) {
        const int rg = row0 + wm * 64 + mt * 16 + qd * 4 + r;
        const int b = rg >> 9, n = rg & 511;
        vco[(((size_t)b * 12 + hh) * 512 + n) * 64 + d] = acc[mt][nt][r];
      }
    }
  }
}

// Output GEMM + bias. grid (6, NB*32)
__global__ __launch_bounds__(256) void gemm_out(
    const ushort_t* __restrict__ A, const ushort_t* __restrict__ Bt,
    const float* __restrict__ bo, float* __restrict__ C)
{
  GEMM_MAINLOOP(A, Bt, 768)
  #pragma unroll
  for (int mt = 0; mt < 4; ++mt) {
    #pragma unroll
    for (int nt = 0; nt < 4; ++nt) {
      const int cg = col0 + wn * 64 + nt * 16 + l15;
      #pragma unroll
      for (int r = 0; r < 4; ++r) {
        const int rg = row0 + wm * 64 + mt * 16 + qd * 4 + r;
        C[(size_t)rg * 768 + cg] = acc[mt][nt][r] + bo[cg];
      }
    }
  }
}

// ---------------------------------------------------------------------------
// Fused k-pool chain + kv partials. grid (16, 12, NB), 256 thr.
// ---------------------------------------------------------------------------
__device__ __forceinline__ void mlp_stage(
    const ushort_t* __restrict__ inb, ushort_t* __restrict__ outb,
    const ushort_t* __restrict__ Wls, const float* __restrict__ bias,
    const float* __restrict__ g, const float* __restrict__ be,
    int rowbase, int ntiles, int tid)
{
  if (ntiles == 0) return;   // wave-uniform
  const int lane = tid & 63, quad = lane >> 4, l15 = lane & 15;
  float bv[4], gv[4], bev[4];
  #pragma unroll
  for (int nt = 0; nt < 4; ++nt) {
    const int c = nt * 16 + l15;
    bv[nt] = bias[c]; gv[nt] = g[c]; bev[nt] = be[c];
  }
  f32x4 a2[2][4];
  #pragma unroll
  for (int mt = 0; mt < 2; ++mt)
    #pragma unroll
    for (int nt = 0; nt < 4; ++nt)
      a2[mt][nt] = f32x4{bv[nt], bv[nt], bv[nt], bv[nt]};

  #pragma unroll
  for (int ks = 0; ks < 2; ++ks) {
    short8 af[2], bfr[4];
    #pragma unroll
    for (int mt = 0; mt < 2; ++mt)
      if (mt < ntiles)
        af[mt] = *(const short8*)&inb[(rowbase + mt * 16 + l15) * 72 + ks * 32 + quad * 8];
    #pragma unroll
    for (int nt = 0; nt < 4; ++nt)
      bfr[nt] = *(const short8*)&Wls[(nt * 16 + l15) * 72 + ks * 32 + quad * 8];
    #pragma unroll
    for (int mt = 0; mt < 2; ++mt)
      if (mt < ntiles)
        #pragma unroll
        for (int nt = 0; nt < 4; ++nt)
          a2[mt][nt] = __builtin_amdgcn_mfma_f32_16x16x32_bf16(af[mt], bfr[nt], a2[mt][nt], 0, 0, 0);
  }

  #pragma unroll
  for (int mt = 0; mt < 2; ++mt) {
    if (mt >= ntiles) continue;
    #pragma unroll
    for (int r = 0; r < 4; ++r) {
      float sum = a2[mt][0][r] + a2[mt][1][r] + a2[mt][2][r] + a2[mt][3][r];
      #pragma unroll
      for (int m = 1; m < 16; m <<= 1) sum += __shfl_xor(sum, m, 64);
      const float mu = sum * 0.015625f;
      float dv[4], var = 0.f;
      #pragma unroll
      for (int nt = 0; nt < 4; ++nt) { dv[nt] = a2[mt][nt][r] - mu; var += dv[nt] * dv[nt]; }
      #pragma unroll
      for (int m = 1; m < 16; m <<= 1) var += __shfl_xor(var, m, 64);
      const float rstd = rsqrtf(var * 0.015625f + 1e-5f);
      const int rl = rowbase + mt * 16 + quad * 4 + r;
      #pragma unroll
      for (int nt = 0; nt < 4; ++nt) {
        const float z = dv[nt] * rstd * gv[nt] + bev[nt];
        outb[rl * 72 + nt * 16 + l15] = f2bf(gelu_exact(z));
      }
    }
  }
}

__device__ __forceinline__ void pool_pairs(
    const ushort_t* __restrict__ inb, ushort_t* __restrict__ outb,
    int outRows, int tid)
{
  for (int idx = tid; idx < outRows * 8; idx += 256) {
    const int rl = idx >> 3, ch = idx & 7;
    short8 a = *(const short8*)&inb[(2 * rl) * 72 + ch * 8];
    short8 b = *(const short8*)&inb[(2 * rl + 1) * 72 + ch * 8];
    short8 o;
    #pragma unroll
    for (int e = 0; e < 8; ++e)
      o[e] = (short)f2bf(0.5f * (bf2f((ushort_t)a[e]) + bf2f((ushort_t)b[e])));
    *(short8*)&outb[rl * 72 + ch * 8] = o;
  }
}

__global__ __launch_bounds__(256) void pool_kv_fused(
    const ushort_t* __restrict__ k16, const float* __restrict__ vc,
    const ushort_t* __restrict__ pWt,
    const float* __restrict__ pb, const float* __restrict__ pg,
    const float* __restrict__ pbe,
    float* __restrict__ kvp, float* __restrict__ ksp)
{
  __shared__ ushort_t Wl[3 * 64 * 72];   // 27.0 KB
  __shared__ ushort_t bufA[128 * 72];    // 18.0 KB
  __shared__ ushort_t bufB[128 * 72];    // 18.0 KB
  __shared__ float    vs[32 * 64];       //  8.0 KB
  const int tid = threadIdx.x;
  const int x = blockIdx.x;
  const int h = blockIdx.y;
  const int bb = blockIdx.z;
  const ushort_t* kin = k16 + (size_t)bb * 3145728;
  const float* vp = vc + (size_t)bb * 393216 + ((size_t)h * 512 + x * 32) * 64;

  {
    const uint_t* ws = (const uint_t*)pWt;
    for (int i = tid; i < 6144; i += 256) {
      const int s = i >> 11, rem = i & 2047, r = rem >> 5, c = rem & 31;
      ((uint_t*)(Wl + (s * 64 + r) * 72))[c] = ws[i];
    }
  }
  #pragma unroll
  for (int j = 0; j < 4; ++j) {
    const int idx = j * 256 + tid;
    const int rl = idx >> 3, ch = idx & 7;
    const ushort_t* p = kin + (size_t)h * 64 + (size_t)(2 * (x * 128 + rl)) * 768 + ch * 8;
    short8 a = *(const short8*)p;
    short8 b2 = *(const short8*)(p + 768);
    short8 o;
    #pragma unroll
    for (int e = 0; e < 8; ++e)
      o[e] = (short)f2bf(0.5f * (bf2f((ushort_t)a[e]) + bf2f((ushort_t)b2[e])));
    *(short8*)&bufA[rl * 72 + ch * 8] = o;
  }
  #pragma unroll
  for (int i = 0; i < 2; ++i)
    ((float4*)vs)[tid + 256 * i] = ((const float4*)vp)[tid + 256 * i];
  __syncthreads();

  const int w = tid >> 6;
  mlp_stage(bufA, bufB, Wl, pb, pg, pbe, w * 32, 2, tid);
  __syncthreads();
  pool_pairs(bufB, bufA, 64, tid);
  __syncthreads();
  mlp_stage(bufA, bufB, Wl + 64 * 72, pb + 64, pg + 64, pbe + 64, w * 16, 1, tid);
  __syncthreads();
  pool_pairs(bufB, bufA, 32, tid);
  __syncthreads();
  mlp_stage(bufA, bufB, Wl + 128 * 72, pb + 128, pg + 128, pbe + 128,
            w * 16, (w < 2) ? 1 : 0, tid);
  __syncthreads();

  const int e = tid & 63;
  const int dg = tid >> 6;
  float acc[16] = {};
  float accs = 0.f;
  for (int nn = 0; nn < 32; ++nn) {
    const float vv = vs[nn * 64 + e];
    #pragma unroll
    for (int j = 0; j < 16; ++j)
      acc[j] += bf2f(bufB[nn * 72 + dg * 16 + j]) * vv;
    if (tid < 64) accs += bf2f(bufB[nn * 72 + tid]);
  }
  float* o = kvp + (size_t)bb * 786432 + ((size_t)h * 16 + x) * 4096;
  #pragma unroll
  for (int j = 0; j < 16; ++j)
    o[(dg * 16 + j) * 64 + e] = acc[j];
  if (tid < 64) ksp[(size_t)bb * 12288 + (h * 16 + x) * 64 + tid] = accs;
}

// reduce partials -> kvxT bf16 [bb][h][80][64]. grid (240, NB).
__global__ __launch_bounds__(256) void kv_reduce_t(
    const float* __restrict__ kvp, const float* __restrict__ ksp,
    ushort_t* __restrict__ kvxT)
{
  const int bb = blockIdx.y;
  kvp  += (size_t)bb * 786432;
  ksp  += (size_t)bb * 12288;
  kvxT += (size_t)bb * 61440;
  const int idx = blockIdx.x * 256 + threadIdx.x;   // < 61440
  const int h = idx / 5120;
  const int rem = idx - h * 5120;
  const int er = rem >> 6, d = rem & 63;
  const float scale = 0.044194173824159216f;  // 1/sqrt(512)
  float val = 0.f;
  if (er < 64) {
    float s = 0.f;
    #pragma unroll
    for (int c = 0; c < 16; ++c) s += kvp[((size_t)h * 16 + c) * 4096 + d * 64 + er];
    val = s * scale;
  } else if (er == 64) {
    float s = 0.f;
    #pragma unroll
    for (int c = 0; c < 16; ++c) s += ksp[(h * 16 + c) * 64 + d];
    val = s * scale;
  }
  kvxT[idx] = f2bf(val);
}

// ---------------------------------------------------------------------------
// Fused MFMA attention-apply + 3 expansion MLPs.
// grid (32, 12, NB): 128 tokens x 1 head per block. Writes bf16 (n,768).
// ---------------------------------------------------------------------------
__global__ __launch_bounds__(256) void attn_exp_mfma(
    const ushort_t* __restrict__ q16, const ushort_t* __restrict__ kvxT,
    const ushort_t* __restrict__ eWt,
    const float* __restrict__ eb, const float* __restrict__ eg,
    const float* __restrict__ ebe, ushort_t* __restrict__ out16)
{
  __shared__ ushort_t Wl[3 * 64 * 72];
  __shared__ ushort_t tl[128 * 72];
  const int tid = threadIdx.x;
  const int h = blockIdx.y;
  const int bb = blockIdx.z;
  const int row0 = blockIdx.x * 128;
  q16   += (size_t)bb * 3145728;
  out16 += (size_t)bb * 3145728;
  const ushort_t* kvx = kvxT + (size_t)bb * 61440 + (size_t)h * 5120;

  {
    const uint_t* ws = (const uint_t*)eWt;
    for (int i = tid; i < 6144; i += 256) {
      const int s = i >> 11, rem = i & 2047, r = rem >> 5, c = rem & 31;
      ((uint_t*)(Wl + (s * 64 + r) * 72))[c] = ws[i];
    }
  }
  __syncthreads();

  const int w = tid >> 6, lane = tid & 63;
  const int quad = lane >> 4, l15 = lane & 15;

  f32x4 acc[2][5] = {};
  #pragma unroll
  for (int ks = 0; ks < 2; ++ks) {
    short8 af[2], bfr[5];
    #pragma unroll
    for (int mt = 0; mt < 2; ++mt) {
      const int rg = row0 + w * 32 + mt * 16 + l15;
      af[mt] = *(const short8*)(q16 + (size_t)rg * 768 + h * 64 + ks * 32 + quad * 8);
    }
    #pragma unroll
    for (int nt = 0; nt < 5; ++nt)
      bfr[nt] = *(const short8*)(kvx + (nt * 16 + l15) * 64 + ks * 32 + quad * 8);
    #pragma unroll
    for (int mt = 0; mt < 2; ++mt)
      #pragma unroll
      for (int nt = 0; nt < 5; ++nt)
        acc[mt][nt] = __builtin_amdgcn_mfma_f32_16x16x32_bf16(af[mt], bfr[nt], acc[mt][nt], 0, 0, 0);
  }

  float t[2][4][4];
  #pragma unroll
  for (int mt = 0; mt < 2; ++mt)
    #pragma unroll
    for (int r = 0; r < 4; ++r) {
      const float den = __shfl(acc[mt][4][r], lane & 48, 64) + 1e-6f;
      const float inv = __builtin_amdgcn_rcpf(den);
      #pragma unroll
      for (int nt = 0; nt < 4; ++nt)
        t[mt][nt][r] = acc[mt][nt][r] * inv;
    }

  for (int s = 2; s >= 0; --s) {
    __syncthreads();
    #pragma unroll
    for (int mt = 0; mt < 2; ++mt)
      #pragma unroll
      for (int nt = 0; nt < 4; ++nt)
        #pragma unroll
        for (int r = 0; r < 4; ++r)
          tl[(w * 32 + mt * 16 + quad * 4 + r) * 72 + nt * 16 + l15] = f2bf(t[mt][nt][r]);
    __syncthreads();

    float bv[4], gv[4], bev[4];
    #pragma unroll
    for (int nt = 0; nt < 4; ++nt) {
      const int c = s * 64 + nt * 16 + l15;
      bv[nt] = eb[c]; gv[nt] = eg[c]; bev[nt] = ebe[c];
    }
    f32x4 a2[2][4];
    #pragma unroll
    for (int mt = 0; mt < 2; ++mt)
      #pragma unroll
      for (int nt = 0; nt < 4; ++nt)
        a2[mt][nt] = f32x4{bv[nt], bv[nt], bv[nt], bv[nt]};

    #pragma unroll
    for (int ks = 0; ks < 2; ++ks) {
      short8 af[2], bfr[4];
      #pragma unroll
      for (int mt = 0; mt < 2; ++mt)
        af[mt] = *(const short8*)&tl[(w * 32 + mt * 16 + l15) * 72 + ks * 32 + quad * 8];
      #pragma unroll
      for (int nt = 0; nt < 4; ++nt)
        bfr[nt] = *(const short8*)&Wl[(s * 64 + nt * 16 + l15) * 72 + ks * 32 + quad * 8];
      #pragma unroll
      for (int mt = 0; mt < 2; ++mt)
        #pragma unroll
        for (int nt = 0; nt < 4; ++nt)
          a2[mt][nt] = __builtin_amdgcn_mfma_f32_16x16x32_bf16(af[mt], bfr[nt], a2[mt][nt], 0, 0, 0);
    }

    #pragma unroll
    for (int mt = 0; mt < 2; ++mt)
      #pragma unroll
      for (int r = 0; r < 4; ++r) {
        float sum = a2[mt][0][r] + a2[mt][1][r] + a2[mt][2][r] + a2[mt][3][r];
        #pragma unroll
        for (int m = 1; m < 16; m <<= 1) sum += __shfl_xor(sum, m, 64);
        const float mu = sum * 0.015625f;
        float dv[4], var = 0.f;
        #pragma unroll
        for (int nt = 0; nt < 4; ++nt) { dv[nt] = a2[mt][nt][r] - mu; var += dv[nt] * dv[nt]; }
        #pragma unroll
        for (int m = 1; m < 16; m <<= 1) var += __shfl_xor(var, m, 64);
        const float rstd = rsqrtf(var * 0.015625f + 1e-5f);
        #pragma unroll
        for (int nt = 0; nt < 4; ++nt) {
          const float z = dv[nt] * rstd * gv[nt] + bev[nt];
          t[mt][nt][r] = gelu_exact(z);
        }
      }
  }

  #pragma unroll
  for (int mt = 0; mt < 2; ++mt)
    #pragma unroll
    for (int nt = 0; nt < 4; ++nt)
      #pragma unroll
      for (int r = 0; r < 4; ++r) {
        const int rg = row0 + w * 32 + mt * 16 + quad * 4 + r;
        out16[(size_t)rg * 768 + h * 64 + nt * 16 + l15] = f2bf(t[mt][nt][r]);
      }
}

// ---------------------------------------------------------------------------
// launch
// ---------------------------------------------------------------------------
extern "C" void kernel_launch(void* const* d_in, const int* in_sizes, int n_in,
                              void* d_out, int out_size, void* d_ws, size_t ws_size,
                              hipStream_t stream)
{
  const float* x   = (const float*)d_in[0];
  const float* Wq  = (const float*)d_in[1];
  const float* Wk  = (const float*)d_in[2];
  const float* Wv  = (const float*)d_in[3];
  const float* pW  = (const float*)d_in[4];
  const float* pb  = (const float*)d_in[5];
  const float* pg  = (const float*)d_in[6];
  const float* pbe = (const float*)d_in[7];
  const float* eW  = (const float*)d_in[8];
  const float* eb  = (const float*)d_in[9];
  const float* eg  = (const float*)d_in[10];
  const float* ebe = (const float*)d_in[11];
  const float* Wo  = (const float*)d_in[12];
  const float* bo  = (const float*)d_in[13];
  float* outp = (float*)d_out;

  // ---- workspace: fixed weight area + NB-batch chunk area ----
  unsigned char* wsb = (unsigned char*)d_ws;
  ushort_t* WqkvT = (ushort_t*)(wsb + 0);              // 3,538,944
  ushort_t* WoT   = (ushort_t*)(wsb + 3538944);        // 1,179,648
  ushort_t* Wt6   = (ushort_t*)(wsb + 4718592);        //    49,152
  const size_t CB   = 4767744;                         // chunk base
  const size_t PERB = 26861568;                        // bytes per batch

  int NB;
  if      (ws_size >= CB + 8 * PERB) NB = 8;
  else if (ws_size >= CB + 4 * PERB) NB = 4;
  else if (ws_size >= CB + 2 * PERB) NB = 2;
  else if (ws_size >= CB + 1 * PERB) NB = 1;
  else return;

  unsigned char* cb = wsb + CB;
  ushort_t* xb16 = (ushort_t*)(cb);                                  // NB*6,291,456
  ushort_t* q16  = (ushort_t*)(cb + (size_t)NB *  6291456);          // NB*6,291,456
  ushort_t* k16  = (ushort_t*)(cb + (size_t)NB * 12582912);          // NB*6,291,456
  float*    vc   = (float*)   (cb + (size_t)NB * 18874368);          // NB*1,572,864
  ushort_t* kc_a = (ushort_t*)(cb + (size_t)NB * 20447232);          // NB*3,145,728 (kvp)
  ushort_t* kc_b = (ushort_t*)(cb + (size_t)NB * 23592960);          // NB*1,572,864 (ksp)
  ushort_t* kvxT = (ushort_t*)(cb + (size_t)NB * 25952256);          // NB*  122,880
  ushort_t* x8   = (ushort_t*)(cb + (size_t)NB * 26075136);          // NB*  786,432
  float* kvp = (float*)kc_a;
  float* ksp = (float*)kc_b;
  ushort_t* ao16 = xb16;

  const ushort_t* pWt = Wt6;
  const ushort_t* eWt = Wt6 + 3 * 4096;
  const size_t SB = (size_t)N_ * DIM_;

  transpose_w_bf16<<<dim3(24, 24), 256, 0, stream>>>(Wq, WqkvT);
  transpose_w_bf16<<<dim3(24, 24), 256, 0, stream>>>(Wk, WqkvT + 768 * 768);
  transpose_w_bf16<<<dim3(24, 24), 256, 0, stream>>>(Wv, WqkvT + 2 * 768 * 768);
  transpose_w_bf16<<<dim3(24, 24), 256, 0, stream>>>(Wo, WoT);
  transpose64_bf16<<<6, 256, 0, stream>>>(pW, eW, Wt6);

  const ushort_t* WvT = WqkvT + 2 * 768 * 768;

  for (int b0 = 0; b0 < B_; b0 += NB) {
    const float* xc = x + (size_t)b0 * SB;
    float* oc = outp + (size_t)b0 * SB;

    conv_pool8<<<NB * 512, 192, 0, stream>>>(xc, xb16, x8);
    gemm_qkv<<<dim3(12, NB * 32), 256, 0, stream>>>(xb16, WqkvT, q16, k16);
    gemm_v<<<dim3(6, NB * 4), 256, 0, stream>>>(x8, WvT, vc);

    pool_kv_fused<<<dim3(16, 12, NB), 256, 0, stream>>>(k16, vc, pWt,
                                                        pb, pg, pbe, kvp, ksp);
    kv_reduce_t<<<dim3(240, NB), 256, 0, stream>>>(kvp, ksp, kvxT);

    attn_exp_mfma<<<dim3(32, 12, NB), 256, 0, stream>>>(q16, kvxT, eWt,
                                                        eb, eg, ebe, ao16);

    gemm_out<<<dim3(6, NB * 32), 256, 0, stream>>>(ao16, WoT, bo, oc);
  }
}